// Round 8
// baseline (790.003 us; speedup 1.0000x reference)
//
#include <hip/hip_runtime.h>

#define BATCH 4096
#define IMG_PER_BLK 4
#define NGROUPS (BATCH / IMG_PER_BLK)    // 1024 groups of 4 images

typedef __attribute__((ext_vector_type(8))) short bf16x8;
typedef __attribute__((ext_vector_type(4))) float f32x4;
typedef __attribute__((ext_vector_type(4))) short short4v;

// ---------------- ws layout (floats) ----------------
// slots: [0]=xmax,[1..5]=act maxes (uint bits), [6]=inv_sw2, [7]=inv_sw3, [16]=barrier counter
constexpr int OFF_W1Q = 256;
constexpr int OFF_W2Q = OFF_W1Q + 288;
constexpr int OFF_W3Q = OFF_W2Q + 18432;
constexpr int OFF_W4Q = OFF_W3Q + 1024;
constexpr int OFF_W5Q = OFF_W4Q + 2304;
constexpr int OFF_WLQ = OFF_W5Q + 1024;
constexpr int OFF_B1Q = OFF_WLQ + 640;
constexpr int OFF_B2Q = OFF_B1Q + 32;
constexpr int OFF_B3Q = OFF_B2Q + 64;
constexpr int OFF_B4Q = OFF_B3Q + 16;
constexpr int OFF_B5Q = OFF_B4Q + 16;
constexpr int OFF_BLQ = OFF_B5Q + 64;
constexpr int OFF_W2I = 24576;                   // shorts, 18432 -> 9216 floats
constexpr int OFF_W3I = OFF_W2I + 9216;          // shorts, 1024 -> 512 floats
constexpr size_t OFF_V2   = 40960;                               // B*4096 f32 (clipped conv2 out)
constexpr size_t OFF_SK2I = OFF_V2 + (size_t)BATCH * 4096;       // B*1024 shorts
constexpr size_t OFF_A3   = OFF_SK2I + (size_t)BATCH * 512;      // B*1024 f32
constexpr size_t OFF_A4   = OFF_A3 + (size_t)BATCH * 1024;       // B*256 f32
constexpr size_t OFF_A5   = OFF_A4 + (size_t)BATCH * 256;        // B*1024 f32
constexpr size_t WS_FLOATS_NEEDED = OFF_A5 + (size_t)BATCH * 1024;

#define A1_S   40            // a1 LDS tile ic-stride in shorts (80B)
#define A1_ROW (18 * A1_S)

// ---------------- helpers ----------------
__device__ __forceinline__ float fq(float x, float scale, float maxv) {
    float q = rintf(x * scale);                 // round-half-even == jnp.round
    q = fminf(fmaxf(q, -maxv), maxv);
    return q / scale;
}

__device__ __forceinline__ short int_to_bf16_bits(float v) {   // exact for small ints
    return (short)(__float_as_uint(v) >> 16);
}

__device__ __forceinline__ float bf16_bits_to_float(short b) {
    return __uint_as_float(((unsigned)(unsigned short)b) << 16);
}

__device__ __forceinline__ unsigned ld_slot(const unsigned* p) {
    return __hip_atomic_load(p, __ATOMIC_RELAXED, __HIP_MEMORY_SCOPE_AGENT);
}

__device__ __forceinline__ void wave_max_atomic(float v, unsigned* dst) {
#pragma unroll
    for (int off = 32; off; off >>= 1) v = fmaxf(v, __shfl_xor(v, off, 64));
    if ((threadIdx.x & 63) == 0) atomicMax(dst, __float_as_uint(v));
}

// manual grid barrier: cumulative arrival counter, phase p in 1..6, goal = p*gridDim
__device__ __forceinline__ void gsync(unsigned* cnt, unsigned goal) {
    __syncthreads();
    if (threadIdx.x == 0) {
        __hip_atomic_fetch_add(cnt, 1u, __ATOMIC_ACQ_REL, __HIP_MEMORY_SCOPE_AGENT);
        while (__hip_atomic_load(cnt, __ATOMIC_ACQUIRE, __HIP_MEMORY_SCOPE_AGENT) < goal)
            __builtin_amdgcn_s_sleep(2);
    }
    __syncthreads();
}

// shared conv1 arithmetic (bitwise identical across phases)
__device__ __forceinline__ void stage_x_tile(const float* xi, float sx, float* xt, int tid) {
    for (int i = tid; i < 1024; i += 256) {
        int ih = i >> 5, iw = i & 31;
        xt[(ih + 1) * 34 + (iw + 1)] = fq(xi[i], sx, 127.f);
    }
}

__device__ __forceinline__ void conv1_pos(const float* xt, const float* w1q, const float* b1q,
                                          int tid, float out[32]) {
    int oh = tid >> 4, ow = tid & 15;
    float in[9];
#pragma unroll
    for (int kh = 0; kh < 3; kh++)
#pragma unroll
        for (int kw = 0; kw < 3; kw++)
            in[kh * 3 + kw] = xt[(oh * 2 + kh) * 34 + (ow * 2 + kw)];
#pragma unroll
    for (int oc = 0; oc < 32; oc++) {
        float acc = b1q[oc];
#pragma unroll
        for (int k = 0; k < 9; k++) acc = fmaf(in[k], w1q[oc * 9 + k], acc);
        out[oc] = fminf(fmaxf(acc, 0.f), 10.f);
    }
}

// ---------------- weight fake-quant (12 tensors, one block each) ----------------
struct WeightArgs {
    const float* src[12];
    float*       dst[12];
    int          n[12];
    float        maxv[12];
};

__global__ __launch_bounds__(256) void k_weights(WeightArgs a) {
    int t = blockIdx.x;
    const float* s = a.src[t];
    float* d = a.dst[t];
    int n = a.n[t];
    float maxv = a.maxv[t];
    __shared__ float red[256];
    int tid = threadIdx.x;
    float m = 0.f;
    for (int i = tid; i < n; i += 256) m = fmaxf(m, fabsf(s[i]));
    red[tid] = m;
    __syncthreads();
    for (int sft = 128; sft > 0; sft >>= 1) {
        if (tid < sft) red[tid] = fmaxf(red[tid], red[tid + sft]);
        __syncthreads();
    }
    float scale = maxv / red[0];
    for (int i = tid; i < n; i += 256) {
        float q = rintf(s[i] * scale);
        q = fminf(fmaxf(q, -maxv), maxv);
        d[i] = q / scale;
    }
}

__global__ __launch_bounds__(256) void k_prep_w2(const float* __restrict__ w2,
                                                 short* __restrict__ w2i,
                                                 float* __restrict__ inv_sw_slot) {
    __shared__ float red[256];
    int tid = threadIdx.x;
    float m = 0.f;
    for (int i = tid; i < 18432; i += 256) m = fmaxf(m, fabsf(w2[i]));
    red[tid] = m;
    __syncthreads();
    for (int s = 128; s > 0; s >>= 1) {
        if (tid < s) red[tid] = fmaxf(red[tid], red[tid + s]);
        __syncthreads();
    }
    float maxw = red[0];
    float sw = 127.f / maxw;
    if (tid == 0) *inv_sw_slot = maxw / 127.f;
    for (int i = tid; i < 18432; i += 256) {
        int oc = i / 288, r = i % 288, ic = r / 9, t = r % 9;
        float q = rintf(w2[i] * sw);
        q = fminf(fmaxf(q, -127.f), 127.f);
        w2i[oc * 288 + t * 32 + ic] = int_to_bf16_bits(q);
    }
}

__global__ __launch_bounds__(256) void k_prep_w3(const float* __restrict__ w3,
                                                 short* __restrict__ w3i,
                                                 float* __restrict__ inv_sw_slot) {
    __shared__ float red[256];
    int tid = threadIdx.x;
    float m = 0.f;
    for (int i = tid; i < 1024; i += 256) m = fmaxf(m, fabsf(w3[i]));
    red[tid] = m;
    __syncthreads();
    for (int s = 128; s > 0; s >>= 1) {
        if (tid < s) red[tid] = fmaxf(red[tid], red[tid + s]);
        __syncthreads();
    }
    float maxw = red[0];
    float sw = 127.f / maxw;
    if (tid == 0) *inv_sw_slot = maxw / 127.f;
    for (int i = tid; i < 1024; i += 256) {
        float q = rintf(w3[i] * sw);
        q = fminf(fmaxf(q, -127.f), 127.f);
        w3i[i] = int_to_bf16_bits(q);
    }
}

// ---------------- persistent mega-kernel (manual grid barrier) ----------------
struct MegaArgs {
    const float* x;
    const float* w1q; const float* b1q;
    const short* w2i; const float* b2q;
    const short* w3i; const float* b3q;
    const float* w4q; const float* b4q;
    const float* w5q; const float* b5q;
    const float* wlq; const float* blq;
    const float* invsw2p; const float* invsw3p;
    unsigned* slots;
    float* v2w; short* sk2w; float* a3w; float* a4w; float* a5w;
    float* out;
};

__global__ __launch_bounds__(256, 4) void k_mega(MegaArgs a) {
    // LDS: xt 4624 | a1t 25920 | a2q 8192 | sk1s 1024  = 39760 B
    __shared__ __align__(16) char smem[39760];
    float* xt   = (float*)smem;
    short* a1t  = (short*)(smem + 4624);
    short* a2q  = (short*)(smem + 30544);
    float* sk1s = (float*)(smem + 38736);

    int tid = threadIdx.x, lane = tid & 63, wv = tid >> 6;
    unsigned nblk = gridDim.x;
    unsigned* cnt = a.slots + 16;

    // zero halos once (interiors overwritten per image; halos persist across phases)
    for (int i = tid; i < 1156; i += 256) xt[i] = 0.f;
    for (int i = tid; i < 6480; i += 256) ((int*)a1t)[i] = 0;

    // per-wave weight fragments (w2i/w3i ready before launch)
    int oc2 = wv * 16 + (lane & 15);
    bf16x8 bw2[9];
#pragma unroll
    for (int t = 0; t < 9; t++)
        bw2[t] = *(const bf16x8*)(a.w2i + oc2 * 288 + t * 32 + (lane >> 4) * 8);
    float bias2 = a.b2q[oc2];
    bf16x8 bw3[2];
#pragma unroll
    for (int t = 0; t < 2; t++)
        bw3[t] = *(const bf16x8*)(a.w3i + (lane & 15) * 64 + t * 32 + (lane >> 4) * 8);
    float bias3 = a.b3q[lane & 15];

    // ---- P0: absmax(x) ----
    {
        const float4* xv = (const float4*)a.x;
        float m = 0.f;
        for (unsigned i = blockIdx.x * 256 + tid; i < BATCH * 256; i += nblk * 256) {
            float4 v = xv[i];
            m = fmaxf(m, fmaxf(fmaxf(fabsf(v.x), fabsf(v.y)), fmaxf(fabsf(v.z), fabsf(v.w))));
        }
        wave_max_atomic(m, a.slots + 0);
    }
    gsync(cnt, nblk * 1);
    float sx = 127.f / __uint_as_float(ld_slot(a.slots + 0));

    // ---- P1: conv1 -> m1 (compute only) ----
    {
        float lmax = 0.f;
        for (unsigned g = blockIdx.x; g < NGROUPS; g += nblk)
            for (int li = 0; li < IMG_PER_BLK; li++) {
                int img = g * IMG_PER_BLK + li;
                __syncthreads();
                stage_x_tile(a.x + (size_t)img * 1024, sx, xt, tid);
                __syncthreads();
                float o1[32];
                conv1_pos(xt, a.w1q, a.b1q, tid, o1);
#pragma unroll
                for (int c = 0; c < 32; c++) lmax = fmaxf(lmax, o1[c]);
            }
        wave_max_atomic(lmax, a.slots + 1);
    }
    gsync(cnt, nblk * 2);
    float m1 = __uint_as_float(ld_slot(a.slots + 1));
    float s1 = 127.f / m1;
    float inv2 = (m1 / 127.f) * (*a.invsw2p);

    // ---- P2: conv1 + conv2 (MFMA), skip1, store clipped v2 -> m2 ----
    {
        short* a1dst = a1t + ((tid >> 4) + 1) * A1_ROW + ((tid & 15) + 1) * A1_S;
        float lmax = 0.f;
        for (unsigned g = blockIdx.x; g < NGROUPS; g += nblk)
            for (int li = 0; li < IMG_PER_BLK; li++) {
                int img = g * IMG_PER_BLK + li;
                __syncthreads();
                stage_x_tile(a.x + (size_t)img * 1024, sx, xt, tid);
                __syncthreads();
                float o1[32];
                conv1_pos(xt, a.w1q, a.b1q, tid, o1);
#pragma unroll
                for (int c = 0; c < 8; c++) {
                    short4v v;
                    v.x = int_to_bf16_bits(rintf(o1[c * 4 + 0] * s1));
                    v.y = int_to_bf16_bits(rintf(o1[c * 4 + 1] * s1));
                    v.z = int_to_bf16_bits(rintf(o1[c * 4 + 2] * s1));
                    v.w = int_to_bf16_bits(rintf(o1[c * 4 + 3] * s1));
                    *(short4v*)(a1dst + c * 4) = v;
                }
                if (tid < 64) {        // skip1 = pool(fq(x),5,4,2), monotone fq
                    int soh = tid >> 3, sow = tid & 7;
                    float m = -INFINITY;
                    int h0 = soh * 4 - 2, w0 = sow * 4 - 2;
                    for (int kh = 0; kh < 5; kh++) {
                        int ih = h0 + kh;
                        if (ih < 0 || ih >= 32) continue;
                        for (int kw = 0; kw < 5; kw++) {
                            int iw = w0 + kw;
                            if (iw < 0 || iw >= 32) continue;
                            m = fmaxf(m, xt[(ih + 1) * 34 + (iw + 1)]);
                        }
                    }
                    sk1s[tid] = m;
                }
                __syncthreads();
                float* vo = a.v2w + (size_t)img * 4096;
#pragma unroll
                for (int mb = 0; mb < 4; mb++) {
                    int m = mb * 16 + (lane & 15);
                    int oh = m >> 3, ow = m & 7;
                    const short* abase = a1t + (oh * 2) * A1_ROW + (ow * 2) * A1_S + (lane >> 4) * 8;
                    f32x4 acc = {0.f, 0.f, 0.f, 0.f};
#pragma unroll
                    for (int kh = 0; kh < 3; kh++)
#pragma unroll
                        for (int kw = 0; kw < 3; kw++) {
                            bf16x8 av = *(const bf16x8*)(abase + kh * A1_ROW + kw * A1_S);
                            acc = __builtin_amdgcn_mfma_f32_16x16x32_bf16(av, bw2[kh * 3 + kw], acc, 0, 0, 0);
                        }
#pragma unroll
                    for (int r = 0; r < 4; r++) {
                        int pos = mb * 16 + (lane >> 4) * 4 + r;
                        float v = acc[r] * inv2 + bias2 + sk1s[pos];
                        v = fminf(fmaxf(v, 0.f), 10.f);
                        vo[oc2 * 64 + pos] = v;
                        lmax = fmaxf(lmax, v);
                    }
                }
            }
        wave_max_atomic(lmax, a.slots + 2);
    }
    gsync(cnt, nblk * 3);
    float m2 = __uint_as_float(ld_slot(a.slots + 2));
    float s2 = 127.f / m2;
    float invs2 = m2 / 127.f;
    float inv3 = invs2 * (*a.invsw3p);

    // ---- P3: requantize v2 -> a2q, conv3 (MFMA) -> a3, skip2 -> m3 ----
    {
        float lmax = 0.f;
        for (unsigned g = blockIdx.x; g < NGROUPS; g += nblk)
            for (int li = 0; li < IMG_PER_BLK; li++) {
                int img = g * IMG_PER_BLK + li;
                __syncthreads();
                const float* vi = a.v2w + (size_t)img * 4096;
#pragma unroll
                for (int mb = 0; mb < 4; mb++)
#pragma unroll
                    for (int r = 0; r < 4; r++) {
                        int pos = mb * 16 + (lane >> 4) * 4 + r;
                        float q = fminf(rintf(vi[oc2 * 64 + pos] * s2), 127.f);
                        a2q[pos * 64 + oc2] = int_to_bf16_bits(q);
                    }
                __syncthreads();
                const short* abase = a2q + (wv * 16 + (lane & 15)) * 64 + (lane >> 4) * 8;
                f32x4 acc = {0.f, 0.f, 0.f, 0.f};
#pragma unroll
                for (int t = 0; t < 2; t++) {
                    bf16x8 av = *(const bf16x8*)(abase + t * 32);
                    acc = __builtin_amdgcn_mfma_f32_16x16x32_bf16(av, bw3[t], acc, 0, 0, 0);
                }
                float* a3o = a.a3w + (size_t)img * 1024;
#pragma unroll
                for (int r = 0; r < 4; r++) {
                    int pos = wv * 16 + (lane >> 4) * 4 + r;
                    float v = acc[r] * inv3 + bias3;
                    v = fminf(fmaxf(v, 0.f), 10.f);
                    a3o[(lane & 15) * 64 + pos] = v;
                    lmax = fmaxf(lmax, v);
                }
                // skip2 = pool(q2,3,2,1) as integer bf16 (scale applied at conv5)
                short* sko = a.sk2w + (size_t)img * 1024;
#pragma unroll
                for (int r = 0; r < 4; ++r) {
                    int idx = tid * 4 + r;
                    int c = idx >> 4, pp = idx & 15, soh = pp >> 2, sow = pp & 3;
                    float m = -INFINITY;
                    for (int kh = 0; kh < 3; kh++) {
                        int ih = soh * 2 - 1 + kh;
                        if (ih < 0 || ih >= 8) continue;
                        for (int kw = 0; kw < 3; kw++) {
                            int iw = sow * 2 - 1 + kw;
                            if (iw < 0 || iw >= 8) continue;
                            m = fmaxf(m, bf16_bits_to_float(a2q[(ih * 8 + iw) * 64 + c]));
                        }
                    }
                    sko[idx] = int_to_bf16_bits(m);
                }
            }
        wave_max_atomic(lmax, a.slots + 3);
    }
    gsync(cnt, nblk * 4);
    float m3 = __uint_as_float(ld_slot(a.slots + 3));
    float s3v = 127.f / m3;

    // ---- P4: conv4 -> a4, m4 ----
    {
        float* c4t = (float*)(smem + 4624);           // 1600 f32, a1t region
        for (int i = tid; i < 1600; i += 256) c4t[i] = 0.f;
        float lmax = 0.f;
        for (unsigned g = blockIdx.x; g < NGROUPS; g += nblk)
            for (int li = 0; li < IMG_PER_BLK; li++) {
                int img = g * IMG_PER_BLK + li;
                __syncthreads();
                const float* ai = a.a3w + (size_t)img * 1024;
                for (int i = tid; i < 1024; i += 256) {
                    int ic = i >> 6, p = i & 63, ih = p >> 3, iw = p & 7;
                    c4t[ic * 100 + (ih + 1) * 10 + (iw + 1)] = fq(ai[i], s3v, 127.f);
                }
                __syncthreads();
                int oc = tid >> 4, p = tid & 15, oh = p >> 2, ow = p & 3;
                float acc = a.b4q[oc];
                const float* w = a.w4q + oc * 144;
                for (int ic = 0; ic < 16; ic++) {
                    const float* tin = c4t + ic * 100 + (oh * 2) * 10 + (ow * 2);
                    const float* wc = w + ic * 9;
#pragma unroll
                    for (int kh = 0; kh < 3; kh++)
#pragma unroll
                        for (int kw = 0; kw < 3; kw++)
                            acc += tin[kh * 10 + kw] * wc[kh * 3 + kw];
                }
                float v = fminf(fmaxf(acc, 0.f), 10.f);
                a.a4w[(size_t)img * 256 + tid] = v;
                lmax = fmaxf(lmax, v);
            }
        wave_max_atomic(lmax, a.slots + 4);
    }
    gsync(cnt, nblk * 5);
    float m4 = __uint_as_float(ld_slot(a.slots + 4));
    float s4v = 127.f / m4;

    // ---- P5: conv5 + skip2 -> a5, m5 ----
    {
        float* tin5 = (float*)(smem + 4624);          // 256 f32
        float lmax = 0.f;
        for (unsigned g = blockIdx.x; g < NGROUPS; g += nblk)
            for (int li = 0; li < IMG_PER_BLK; li++) {
                int img = g * IMG_PER_BLK + li;
                __syncthreads();
                tin5[tid] = fq(a.a4w[(size_t)img * 256 + tid], s4v, 127.f);
                __syncthreads();
                int p = tid & 15, ocb = tid >> 4;
                for (int j = 0; j < 4; j++) {
                    int oc = ocb * 4 + j;
                    float acc = a.b5q[oc];
                    const float* w = a.w5q + oc * 16;
#pragma unroll
                    for (int ic = 0; ic < 16; ic++) acc += tin5[ic * 16 + p] * w[ic];
                    acc += bf16_bits_to_float(a.sk2w[(size_t)img * 1024 + oc * 16 + p]) * invs2;
                    float v = fminf(fmaxf(acc, 0.f), 10.f);
                    a.a5w[(size_t)img * 1024 + oc * 16 + p] = v;
                    lmax = fmaxf(lmax, v);
                }
            }
        wave_max_atomic(lmax, a.slots + 5);
    }
    gsync(cnt, nblk * 6);
    float m5 = __uint_as_float(ld_slot(a.slots + 5));
    float s5v = 127.f / m5;

    // ---- P6: head (4 images at once) ----
    {
        float* hlds = (float*)(smem + 4624);          // 256 f32
        int img = tid >> 6, c = tid & 63;
        for (unsigned g = blockIdx.x; g < NGROUPS; g += nblk) {
            size_t gimg = (size_t)g * IMG_PER_BLK + img;
            __syncthreads();
            const float* ai = a.a5w + gimg * 1024 + c * 16;
            float sum = 0.f;
#pragma unroll
            for (int p = 0; p < 16; p++) sum += fq(ai[p], s5v, 127.f);
            hlds[img * 64 + c] = sum * (1.f / 16.f);
            __syncthreads();
            if (c < 10) {
                float acc = a.blq[c];
                const float* w = a.wlq + c * 64;
                for (int ic = 0; ic < 64; ic++) acc = fmaf(hlds[img * 64 + ic], w[ic], acc);
                a.out[gimg * 10 + c] = acc;
            }
        }
    }
}

// ---------------- launch ----------------
extern "C" void kernel_launch(void* const* d_in, const int* in_sizes, int n_in,
                              void* d_out, int out_size, void* d_ws, size_t ws_size,
                              hipStream_t stream) {
    const float* x  = (const float*)d_in[0];
    const float* w1 = (const float*)d_in[1];
    const float* b1 = (const float*)d_in[2];
    const float* w2 = (const float*)d_in[3];
    const float* b2 = (const float*)d_in[4];
    const float* w3 = (const float*)d_in[5];
    const float* b3 = (const float*)d_in[6];
    const float* w4 = (const float*)d_in[7];
    const float* b4 = (const float*)d_in[8];
    const float* w5 = (const float*)d_in[9];
    const float* b5 = (const float*)d_in[10];
    const float* wl = (const float*)d_in[11];
    const float* bl = (const float*)d_in[12];

    if (ws_size < WS_FLOATS_NEEDED * sizeof(float)) return;

    float* ws = (float*)d_ws;
    unsigned* slots = (unsigned*)d_ws;
    short* w2i = (short*)(ws + OFF_W2I);
    short* w3i = (short*)(ws + OFF_W3I);

    hipMemsetAsync(d_ws, 0, 1024, stream);   // zero slots + barrier counter

    WeightArgs wa;
    const float* srcs[12] = {w1, w2, w3, w4, w5, wl, b1, b2, b3, b4, b5, bl};
    const int    ns[12]   = {288, 18432, 1024, 2304, 1024, 640, 32, 64, 16, 16, 64, 10};
    const int    offs[12] = {OFF_W1Q, OFF_W2Q, OFF_W3Q, OFF_W4Q, OFF_W5Q, OFF_WLQ,
                             OFF_B1Q, OFF_B2Q, OFF_B3Q, OFF_B4Q, OFF_B5Q, OFF_BLQ};
    const float  mv[12]   = {127.f, 127.f, 127.f, 127.f, 127.f, 127.f,
                             32767.f, 32767.f, 32767.f, 32767.f, 32767.f, 32767.f};
    for (int i = 0; i < 12; i++) {
        wa.src[i] = srcs[i];
        wa.dst[i] = ws + offs[i];
        wa.n[i] = ns[i];
        wa.maxv[i] = mv[i];
    }
    k_weights<<<12, 256, 0, stream>>>(wa);
    k_prep_w2<<<1, 256, 0, stream>>>(w2, w2i, ws + 6);
    k_prep_w3<<<1, 256, 0, stream>>>(w3, w3i, ws + 7);

    MegaArgs ma;
    ma.x = x;
    ma.w1q = ws + OFF_W1Q;  ma.b1q = ws + OFF_B1Q;
    ma.w2i = w2i;           ma.b2q = ws + OFF_B2Q;
    ma.w3i = w3i;           ma.b3q = ws + OFF_B3Q;
    ma.w4q = ws + OFF_W4Q;  ma.b4q = ws + OFF_B4Q;
    ma.w5q = ws + OFF_W5Q;  ma.b5q = ws + OFF_B5Q;
    ma.wlq = ws + OFF_WLQ;  ma.blq = ws + OFF_BLQ;
    ma.invsw2p = ws + 6;    ma.invsw3p = ws + 7;
    ma.slots = slots;
    ma.v2w = ws + OFF_V2;
    ma.sk2w = (short*)(ws + OFF_SK2I);
    ma.a3w = ws + OFF_A3;
    ma.a4w = ws + OFF_A4;
    ma.a5w = ws + OFF_A5;
    ma.out = (float*)d_out;

    // grid = min(NGROUPS, runtime max co-resident blocks) -> manual barrier is safe
    int perCU = 0;
    if (hipOccupancyMaxActiveBlocksPerMultiprocessor(&perCU, (const void*)k_mega, 256, 0)
            != hipSuccess || perCU < 1)
        perCU = 1;
    int cus = 0, dev = 0;
    hipGetDevice(&dev);
    if (hipDeviceGetAttribute(&cus, hipDeviceAttributeMultiprocessorCount, dev) != hipSuccess
            || cus < 1)
        cus = 256;
    int grid = perCU * cus;
    if (grid > NGROUPS) grid = NGROUPS;

    k_mega<<<grid, 256, 0, stream>>>(ma);
}

// Round 10
// 744.206 us; speedup vs baseline: 1.0615x; 1.0615x over previous
//
#include <hip/hip_runtime.h>

#define BATCH 4096

typedef __attribute__((ext_vector_type(8))) short bf16x8;
typedef __attribute__((ext_vector_type(4))) float f32x4;

// ---------------- ws layout (floats) ----------------
// slots: [0]=xmax,[1..5]=act maxes (uint bits), [6]=inv_sw2, [7]=inv_sw3, [8]=inv_sw1
constexpr int OFF_W1Q = 256;
constexpr int OFF_W2Q = OFF_W1Q + 288;
constexpr int OFF_W3Q = OFF_W2Q + 18432;
constexpr int OFF_W4Q = OFF_W3Q + 1024;
constexpr int OFF_W5Q = OFF_W4Q + 2304;
constexpr int OFF_WLQ = OFF_W5Q + 1024;
constexpr int OFF_B1Q = OFF_WLQ + 640;
constexpr int OFF_B2Q = OFF_B1Q + 32;
constexpr int OFF_B3Q = OFF_B2Q + 64;
constexpr int OFF_B4Q = OFF_B3Q + 16;
constexpr int OFF_B5Q = OFF_B4Q + 16;
constexpr int OFF_BLQ = OFF_B5Q + 64;
constexpr int OFF_W1I = 24576;                       // 1024 shorts = 512 fl
constexpr int OFF_W2I = OFF_W1I + 512;               // 18432 shorts = 9216 fl
constexpr int OFF_W3I = OFF_W2I + 9216;              // 1024 shorts = 512 fl
constexpr size_t OFF_SK1F = 40960;                               // B*64 f32
constexpr size_t OFF_V2   = OFF_SK1F + (size_t)BATCH * 64;       // B*4096 f32
constexpr size_t OFF_SK2I = OFF_V2 + (size_t)BATCH * 4096;       // B*1024 shorts (B*512 fl)
constexpr size_t OFF_A3   = OFF_SK2I + (size_t)BATCH * 512;      // B*1024 f32
constexpr size_t OFF_A4   = OFF_A3 + (size_t)BATCH * 1024;       // B*256 f32
constexpr size_t OFF_A5   = OFF_A4 + (size_t)BATCH * 256;        // B*1024 f32
constexpr size_t WS_FLOATS_NEEDED = OFF_A5 + (size_t)BATCH * 1024;

#define A1_S   40            // a1 LDS tile ic-stride in shorts (80B)
#define A1_ROW (18 * A1_S)

// ---------------- helpers ----------------
__device__ __forceinline__ float fq(float x, float scale, float maxv) {
    float q = rintf(x * scale);                 // round-half-even == jnp.round
    q = fminf(fmaxf(q, -maxv), maxv);
    return q / scale;
}

__device__ __forceinline__ short int_to_bf16_bits(float v) {   // exact for small ints
    return (short)(__float_as_uint(v) >> 16);
}

__device__ __forceinline__ float bf16_bits_to_float(short b) {
    return __uint_as_float(((unsigned)(unsigned short)b) << 16);
}

__device__ __forceinline__ void wave_max_atomic(float v, unsigned* dst) {
#pragma unroll
    for (int off = 32; off; off >>= 1) v = fmaxf(v, __shfl_xor(v, off, 64));
    if ((threadIdx.x & 63) == 0) atomicMax(dst, __float_as_uint(v));
}

// stage integer-level q_x tile (bf16 bits), halo pre-zeroed
__device__ __forceinline__ void stage_xq(const float* xi, float sx, short* xt_q, int tid) {
    for (int i = tid; i < 1024; i += 256) {
        int ih = i >> 5, iw = i & 31;
        float q = rintf(xi[i] * sx);
        q = fminf(fmaxf(q, -127.f), 127.f);
        xt_q[(ih + 1) * 34 + (iw + 1)] = int_to_bf16_bits(q);
    }
}

// build A-tile qx1[pos][32]: taps k=0..8 (k>=9 pre-zeroed, never overwritten)
__device__ __forceinline__ void build_qx1(const short* xt_q, short* qx1, int tid) {
    int oh = tid >> 4, ow = tid & 15;
    short* dst = qx1 + tid * 32;
#pragma unroll
    for (int kh = 0; kh < 3; kh++)
#pragma unroll
        for (int kw = 0; kw < 3; kw++)
            dst[kh * 3 + kw] = xt_q[(oh * 2 + kh) * 34 + (ow * 2 + kw)];
}

// conv1 via exact-integer MFMA: M=256 pos, N=32 oc, K=32 (9 real taps)
__device__ __forceinline__ void conv1_mfma(const short* qx1, const bf16x8 w1b[2],
                                           int lane, int wv, f32x4 acc[4][2]) {
#pragma unroll
    for (int mb = 0; mb < 4; mb++) {
        bf16x8 a = *(const bf16x8*)(qx1 + ((wv * 4 + mb) * 16 + (lane & 15)) * 32
                                    + (lane >> 4) * 8);
#pragma unroll
        for (int nb = 0; nb < 2; nb++)
            acc[mb][nb] = __builtin_amdgcn_mfma_f32_16x16x32_bf16(a, w1b[nb], acc[mb][nb], 0, 0, 0);
    }
}

// ---------------- weight fake-quant (12 tensors, one block each) ----------------
struct WeightArgs {
    const float* src[12];
    float*       dst[12];
    int          n[12];
    float        maxv[12];
};

__global__ __launch_bounds__(256) void k_weights(WeightArgs a) {
    int t = blockIdx.x;
    const float* s = a.src[t];
    float* d = a.dst[t];
    int n = a.n[t];
    float maxv = a.maxv[t];
    __shared__ float red[256];
    int tid = threadIdx.x;
    float m = 0.f;
    for (int i = tid; i < n; i += 256) m = fmaxf(m, fabsf(s[i]));
    red[tid] = m;
    __syncthreads();
    for (int sft = 128; sft > 0; sft >>= 1) {
        if (tid < sft) red[tid] = fmaxf(red[tid], red[tid + sft]);
        __syncthreads();
    }
    float scale = maxv / red[0];
    for (int i = tid; i < n; i += 256) {
        float q = rintf(s[i] * scale);
        q = fminf(fmaxf(q, -maxv), maxv);
        d[i] = q / scale;
    }
}

// w1 [32][9] -> int-level bf16 w1i[oc][32] (taps 0..8, rest 0); inv scale -> slot
__global__ __launch_bounds__(256) void k_prep_w1(const float* __restrict__ w1,
                                                 short* __restrict__ w1i,
                                                 float* __restrict__ inv_sw_slot) {
    __shared__ float red[256];
    int tid = threadIdx.x;
    float m = 0.f;
    for (int i = tid; i < 288; i += 256) m = fmaxf(m, fabsf(w1[i]));
    red[tid] = m;
    __syncthreads();
    for (int s = 128; s > 0; s >>= 1) {
        if (tid < s) red[tid] = fmaxf(red[tid], red[tid + s]);
        __syncthreads();
    }
    float maxw = red[0];
    float sw = 127.f / maxw;
    if (tid == 0) *inv_sw_slot = maxw / 127.f;
    for (int i = tid; i < 1024; i += 256) w1i[i] = 0;
    __syncthreads();
    for (int i = tid; i < 288; i += 256) {
        int oc = i / 9, t = i % 9;
        float q = rintf(w1[i] * sw);
        q = fminf(fmaxf(q, -127.f), 127.f);
        w1i[oc * 32 + t] = int_to_bf16_bits(q);
    }
}

__global__ __launch_bounds__(256) void k_prep_w2(const float* __restrict__ w2,
                                                 short* __restrict__ w2i,
                                                 float* __restrict__ inv_sw_slot) {
    __shared__ float red[256];
    int tid = threadIdx.x;
    float m = 0.f;
    for (int i = tid; i < 18432; i += 256) m = fmaxf(m, fabsf(w2[i]));
    red[tid] = m;
    __syncthreads();
    for (int s = 128; s > 0; s >>= 1) {
        if (tid < s) red[tid] = fmaxf(red[tid], red[tid + s]);
        __syncthreads();
    }
    float maxw = red[0];
    float sw = 127.f / maxw;
    if (tid == 0) *inv_sw_slot = maxw / 127.f;
    for (int i = tid; i < 18432; i += 256) {
        int oc = i / 288, r = i % 288, ic = r / 9, t = r % 9;
        float q = rintf(w2[i] * sw);
        q = fminf(fmaxf(q, -127.f), 127.f);
        w2i[oc * 288 + t * 32 + ic] = int_to_bf16_bits(q);
    }
}

__global__ __launch_bounds__(256) void k_prep_w3(const float* __restrict__ w3,
                                                 short* __restrict__ w3i,
                                                 float* __restrict__ inv_sw_slot) {
    __shared__ float red[256];
    int tid = threadIdx.x;
    float m = 0.f;
    for (int i = tid; i < 1024; i += 256) m = fmaxf(m, fabsf(w3[i]));
    red[tid] = m;
    __syncthreads();
    for (int s = 128; s > 0; s >>= 1) {
        if (tid < s) red[tid] = fmaxf(red[tid], red[tid + s]);
        __syncthreads();
    }
    float maxw = red[0];
    float sw = 127.f / maxw;
    if (tid == 0) *inv_sw_slot = maxw / 127.f;
    for (int i = tid; i < 1024; i += 256) {
        float q = rintf(w3[i] * sw);
        q = fminf(fmaxf(q, -127.f), 127.f);
        w3i[i] = int_to_bf16_bits(q);
    }
}

// ---------------- global abs-max over x ----------------
__global__ __launch_bounds__(256) void k_absmax(const float4* __restrict__ x, int n4,
                                                unsigned* out) {
    float m = 0.f;
    for (int i = blockIdx.x * 256 + threadIdx.x; i < n4; i += gridDim.x * 256) {
        float4 v = x[i];
        m = fmaxf(m, fmaxf(fmaxf(fabsf(v.x), fabsf(v.y)), fmaxf(fabsf(v.z), fabsf(v.w))));
    }
    wave_max_atomic(m, out);
}

// ---------------- s1: conv1 (MFMA) -> m1; skip1 -> fp32 ----------------
__global__ __launch_bounds__(256) void k_s1(const float* __restrict__ x,
                                            const short* __restrict__ w1i,
                                            const float* __restrict__ b1q,
                                            const unsigned* xmaxb,
                                            const float* __restrict__ inv_sw1p,
                                            float* __restrict__ skip1f,
                                            unsigned* m1out) {
    __shared__ short xt_q[34 * 34];
    __shared__ short qx1[256 * 32];
    int tid = threadIdx.x, lane = tid & 63, wv = tid >> 6;
    float sx = 127.f / __uint_as_float(*xmaxb);
    float inv1 = (*inv_sw1p) / sx;
    bf16x8 w1b[2];
#pragma unroll
    for (int nb = 0; nb < 2; nb++)
        w1b[nb] = *(const bf16x8*)(w1i + (nb * 16 + (lane & 15)) * 32 + (lane >> 4) * 8);
    float bias1[2] = {b1q[lane & 15], b1q[16 + (lane & 15)]};

    for (int i = tid; i < 34 * 34; i += 256) xt_q[i] = 0;
    for (int i = tid; i < 256 * 16; i += 256) ((int*)qx1)[i] = 0;

    float lmax = 0.f;
    for (int li = 0; li < 4; li++) {
        int img = blockIdx.x * 4 + li;
        __syncthreads();
        stage_xq(x + (size_t)img * 1024, sx, xt_q, tid);
        __syncthreads();
        build_qx1(xt_q, qx1, tid);
        if (tid < 64) {           // skip1 = q_pool/sx (monotone; exact division)
            int soh = tid >> 3, sow = tid & 7;
            float m = -INFINITY;
            int h0 = soh * 4 - 2, w0 = sow * 4 - 2;
            for (int kh = 0; kh < 5; kh++) {
                int ih = h0 + kh;
                if (ih < 0 || ih >= 32) continue;
                for (int kw = 0; kw < 5; kw++) {
                    int iw = w0 + kw;
                    if (iw < 0 || iw >= 32) continue;
                    m = fmaxf(m, bf16_bits_to_float(xt_q[(ih + 1) * 34 + (iw + 1)]));
                }
            }
            skip1f[img * 64 + tid] = m / sx;
        }
        __syncthreads();
        f32x4 acc[4][2] = {};
        conv1_mfma(qx1, w1b, lane, wv, acc);
#pragma unroll
        for (int mb = 0; mb < 4; mb++)
#pragma unroll
            for (int nb = 0; nb < 2; nb++)
#pragma unroll
                for (int r = 0; r < 4; r++) {
                    float v = acc[mb][nb][r] * inv1 + bias1[nb];
                    lmax = fmaxf(lmax, fminf(fmaxf(v, 0.f), 10.f));
                }
    }
    wave_max_atomic(lmax, m1out);
}

// ---------------- s2: conv1 (MFMA) -> quant a1 -> conv2 (MFMA) + skip1 -> v2, m2 ----------------
__global__ __launch_bounds__(256) void k_s2(const float* __restrict__ x,
                                            const short* __restrict__ w1i,
                                            const float* __restrict__ b1q,
                                            const short* __restrict__ w2i,
                                            const float* __restrict__ b2q,
                                            const float* __restrict__ skip1f,
                                            const unsigned* xmaxb, const unsigned* m1b,
                                            const float* __restrict__ inv_sw1p,
                                            const float* __restrict__ inv_sw2p,
                                            float* __restrict__ v2w,
                                            unsigned* m2out) {
    __shared__ short xt_q[34 * 34];
    __shared__ short qx1[256 * 32];
    __shared__ short a1t[18 * A1_ROW];
    __shared__ float sk1s[64];
    int tid = threadIdx.x, lane = tid & 63, wv = tid >> 6;
    float sx = 127.f / __uint_as_float(*xmaxb);
    float inv1 = (*inv_sw1p) / sx;
    float m1 = __uint_as_float(*m1b);
    float s1q = 127.f / m1;
    float inv2 = (m1 / 127.f) * (*inv_sw2p);

    bf16x8 w1b[2];
#pragma unroll
    for (int nb = 0; nb < 2; nb++)
        w1b[nb] = *(const bf16x8*)(w1i + (nb * 16 + (lane & 15)) * 32 + (lane >> 4) * 8);
    float bias1[2] = {b1q[lane & 15], b1q[16 + (lane & 15)]};
    int oc2 = wv * 16 + (lane & 15);
    bf16x8 bw2[9];
#pragma unroll
    for (int t = 0; t < 9; t++)
        bw2[t] = *(const bf16x8*)(w2i + oc2 * 288 + t * 32 + (lane >> 4) * 8);
    float bias2 = b2q[oc2];

    for (int i = tid; i < 34 * 34; i += 256) xt_q[i] = 0;
    for (int i = tid; i < 256 * 16; i += 256) ((int*)qx1)[i] = 0;
    for (int i = tid; i < 18 * A1_ROW / 2; i += 256) ((int*)a1t)[i] = 0;

    float lmax = 0.f;
    for (int li = 0; li < 4; li++) {
        int img = blockIdx.x * 4 + li;
        __syncthreads();
        stage_xq(x + (size_t)img * 1024, sx, xt_q, tid);
        if (tid < 64) sk1s[tid] = skip1f[img * 64 + tid];
        __syncthreads();
        build_qx1(xt_q, qx1, tid);
        __syncthreads();
        f32x4 acc1[4][2] = {};
        conv1_mfma(qx1, w1b, lane, wv, acc1);
        // quantize conv1 out -> a1t (identical conv1 values as s1 -> all <= m1)
#pragma unroll
        for (int mb = 0; mb < 4; mb++)
#pragma unroll
            for (int nb = 0; nb < 2; nb++)
#pragma unroll
                for (int r = 0; r < 4; r++) {
                    float v = acc1[mb][nb][r] * inv1 + bias1[nb];
                    v = fminf(fmaxf(v, 0.f), 10.f);
                    float q = fminf(rintf(v * s1q), 127.f);
                    int pos = (wv * 4 + mb) * 16 + (lane >> 4) * 4 + r;
                    int oc = nb * 16 + (lane & 15);
                    a1t[((pos >> 4) + 1) * A1_ROW + ((pos & 15) + 1) * A1_S + oc] =
                        int_to_bf16_bits(q);
                }
        __syncthreads();
        // conv2 MFMA
        float* vo = v2w + (size_t)img * 4096;
#pragma unroll
        for (int mb = 0; mb < 4; mb++) {
            int m = mb * 16 + (lane & 15);
            int oh = m >> 3, ow = m & 7;
            const short* abase = a1t + (oh * 2) * A1_ROW + (ow * 2) * A1_S + (lane >> 4) * 8;
            f32x4 acc = {0.f, 0.f, 0.f, 0.f};
#pragma unroll
            for (int kh = 0; kh < 3; kh++)
#pragma unroll
                for (int kw = 0; kw < 3; kw++) {
                    bf16x8 av = *(const bf16x8*)(abase + kh * A1_ROW + kw * A1_S);
                    acc = __builtin_amdgcn_mfma_f32_16x16x32_bf16(av, bw2[kh * 3 + kw], acc, 0, 0, 0);
                }
            float4 vv;
            float* vvp = (float*)&vv;
#pragma unroll
            for (int r = 0; r < 4; r++) {
                int pos = mb * 16 + (lane >> 4) * 4 + r;
                float v = acc[r] * inv2 + bias2 + sk1s[pos];
                v = fminf(fmaxf(v, 0.f), 10.f);
                vvp[r] = v;
                lmax = fmaxf(lmax, v);
            }
            *(float4*)(vo + oc2 * 64 + mb * 16 + (lane >> 4) * 4) = vv;
        }
    }
    wave_max_atomic(lmax, m2out);
}

// ---------------- s3: requant v2 -> conv3 (MFMA) -> a3, skip2 -> m3 ----------------
__global__ __launch_bounds__(256) void k_s3(const float* __restrict__ v2w,
                                            const short* __restrict__ w3i,
                                            const float* __restrict__ b3q,
                                            const unsigned* m2b,
                                            const float* __restrict__ inv_sw3p,
                                            float* __restrict__ a3w,
                                            short* __restrict__ sk2q,
                                            unsigned* m3out) {
    __shared__ short a2q[64 * 64];
    int tid = threadIdx.x, lane = tid & 63, wv = tid >> 6;
    float m2 = __uint_as_float(*m2b);
    float s2 = 127.f / m2;
    float inv3 = (m2 / 127.f) * (*inv_sw3p);
    int oc2 = wv * 16 + (lane & 15);
    bf16x8 bw3[2];
#pragma unroll
    for (int t = 0; t < 2; t++)
        bw3[t] = *(const bf16x8*)(w3i + (lane & 15) * 64 + t * 32 + (lane >> 4) * 8);
    float bias3 = b3q[lane & 15];

    float lmax = 0.f;
    for (int li = 0; li < 4; li++) {
        int img = blockIdx.x * 4 + li;
        __syncthreads();
        const float* vi = v2w + (size_t)img * 4096;
#pragma unroll
        for (int mb = 0; mb < 4; mb++) {
            float4 vv = *(const float4*)(vi + oc2 * 64 + mb * 16 + (lane >> 4) * 4);
            const float* vvp = (const float*)&vv;
#pragma unroll
            for (int r = 0; r < 4; r++) {
                int pos = mb * 16 + (lane >> 4) * 4 + r;
                float q = fminf(rintf(vvp[r] * s2), 127.f);
                a2q[pos * 64 + oc2] = int_to_bf16_bits(q);
            }
        }
        __syncthreads();
        const short* abase = a2q + (wv * 16 + (lane & 15)) * 64 + (lane >> 4) * 8;
        f32x4 acc = {0.f, 0.f, 0.f, 0.f};
#pragma unroll
        for (int t = 0; t < 2; t++) {
            bf16x8 av = *(const bf16x8*)(abase + t * 32);
            acc = __builtin_amdgcn_mfma_f32_16x16x32_bf16(av, bw3[t], acc, 0, 0, 0);
        }
        float* a3o = a3w + (size_t)img * 1024;
#pragma unroll
        for (int r = 0; r < 4; r++) {
            int pos = wv * 16 + (lane >> 4) * 4 + r;
            float v = acc[r] * inv3 + bias3;
            v = fminf(fmaxf(v, 0.f), 10.f);
            a3o[(lane & 15) * 64 + pos] = v;
            lmax = fmaxf(lmax, v);
        }
        // skip2 = pool(q2,3,2,1) int bf16 (scale applied at conv5)
        short* sko = sk2q + (size_t)img * 1024;
#pragma unroll
        for (int r = 0; r < 4; ++r) {
            int idx = tid * 4 + r;
            int c = idx >> 4, pp = idx & 15, soh = pp >> 2, sow = pp & 3;
            float m = -INFINITY;
            for (int kh = 0; kh < 3; kh++) {
                int ih = soh * 2 - 1 + kh;
                if (ih < 0 || ih >= 8) continue;
                for (int kw = 0; kw < 3; kw++) {
                    int iw = sow * 2 - 1 + kw;
                    if (iw < 0 || iw >= 8) continue;
                    m = fmaxf(m, bf16_bits_to_float(a2q[(ih * 8 + iw) * 64 + c]));
                }
            }
            sko[idx] = int_to_bf16_bits(m);
        }
    }
    wave_max_atomic(lmax, m3out);
}

// ---------------- conv4: 3x3, s2 p1, 16->16, 8x8->4x4, clip ----------------
__global__ __launch_bounds__(256) void k_conv4(const float* __restrict__ a3,
                                               const float* __restrict__ w4q,
                                               const float* __restrict__ b4q,
                                               const unsigned* m3bits,
                                               float* __restrict__ a4,
                                               unsigned* actmax) {
    __shared__ float tile[16 * 10 * 10];
    int b = blockIdx.x, tid = threadIdx.x;
    float s3 = 127.f / __uint_as_float(*m3bits);
    for (int i = tid; i < 1600; i += 256) tile[i] = 0.f;
    __syncthreads();
    const float* ai = a3 + (size_t)b * 1024;
    for (int i = tid; i < 1024; i += 256) {
        int ic = i >> 6, p = i & 63, ih = p >> 3, iw = p & 7;
        float q = rintf(ai[i] * s3);
        q = fminf(fmaxf(q, -127.f), 127.f);
        tile[ic * 100 + (ih + 1) * 10 + (iw + 1)] = q / s3;
    }
    __syncthreads();
    int oc = tid >> 4, p = tid & 15, oh = p >> 2, ow = p & 3;
    float acc = b4q[oc];
    const float* w = w4q + oc * 144;
    for (int ic = 0; ic < 16; ic++) {
        const float* tin = tile + ic * 100 + (oh * 2) * 10 + (ow * 2);
        const float* wc = w + ic * 9;
#pragma unroll
        for (int kh = 0; kh < 3; kh++)
#pragma unroll
            for (int kw = 0; kw < 3; kw++)
                acc += tin[kh * 10 + kw] * wc[kh * 3 + kw];
    }
    float v = fminf(fmaxf(acc, 0.f), 10.f);
    a4[(size_t)b * 256 + tid] = v;
    wave_max_atomic(v, actmax);
}

// ---------------- conv5: 1x1, 16->64 on 4x4, +skip2, clip ----------------
__global__ __launch_bounds__(256) void k_conv5(const float* __restrict__ a4,
                                               const float* __restrict__ w5q,
                                               const float* __restrict__ b5q,
                                               const short* __restrict__ sk2q,
                                               const unsigned* m2bits,
                                               const unsigned* m4bits,
                                               float* __restrict__ a5,
                                               unsigned* actmax) {
    __shared__ float tin[256];
    int b = blockIdx.x, tid = threadIdx.x;
    float s4 = 127.f / __uint_as_float(*m4bits);
    float invs2 = __uint_as_float(*m2bits) / 127.f;
    const float* ai = a4 + (size_t)b * 256;
    {
        float q = rintf(ai[tid] * s4);
        q = fminf(fmaxf(q, -127.f), 127.f);
        tin[tid] = q / s4;
    }
    __syncthreads();
    int p = tid & 15, ocb = tid >> 4;
    float lmax = 0.f;
    float* o = a5 + (size_t)b * 1024;
    for (int j = 0; j < 4; j++) {
        int oc = ocb * 4 + j;
        float acc = b5q[oc];
        const float* w = w5q + oc * 16;
#pragma unroll
        for (int ic = 0; ic < 16; ic++) acc += tin[ic * 16 + p] * w[ic];
        acc += bf16_bits_to_float(sk2q[(size_t)b * 1024 + oc * 16 + p]) * invs2;
        float v = fminf(fmaxf(acc, 0.f), 10.f);
        o[oc * 16 + p] = v;
        lmax = fmaxf(lmax, v);
    }
    wave_max_atomic(lmax, actmax);
}

// ---------------- head: fq(a5) -> mean(4x4) -> linear ----------------
__global__ __launch_bounds__(64) void k_head(const float* __restrict__ a5,
                                             const unsigned* m5bits,
                                             const float* __restrict__ wlq,
                                             const float* __restrict__ blq,
                                             float* __restrict__ out) {
    __shared__ float h[64];
    int b = blockIdx.x, c = threadIdx.x;
    float s5 = 127.f / __uint_as_float(*m5bits);
    const float* ai = a5 + (size_t)b * 1024 + c * 16;
    float sum = 0.f;
#pragma unroll
    for (int p = 0; p < 16; p++) sum += fq(ai[p], s5, 127.f);
    h[c] = sum * (1.f / 16.f);
    __syncthreads();
    if (c < 10) {
        float acc = blq[c];
        const float* w = wlq + c * 64;
        for (int ic = 0; ic < 64; ic++) acc = fmaf(h[ic], w[ic], acc);
        out[(size_t)b * 10 + c] = acc;
    }
}

// ---------------- launch ----------------
extern "C" void kernel_launch(void* const* d_in, const int* in_sizes, int n_in,
                              void* d_out, int out_size, void* d_ws, size_t ws_size,
                              hipStream_t stream) {
    const float* x  = (const float*)d_in[0];
    const float* w1 = (const float*)d_in[1];
    const float* b1 = (const float*)d_in[2];
    const float* w2 = (const float*)d_in[3];
    const float* b2 = (const float*)d_in[4];
    const float* w3 = (const float*)d_in[5];
    const float* b3 = (const float*)d_in[6];
    const float* w4 = (const float*)d_in[7];
    const float* b4 = (const float*)d_in[8];
    const float* w5 = (const float*)d_in[9];
    const float* b5 = (const float*)d_in[10];
    const float* wl = (const float*)d_in[11];
    const float* bl = (const float*)d_in[12];

    if (ws_size < WS_FLOATS_NEEDED * sizeof(float)) return;

    float* ws = (float*)d_ws;
    unsigned* slots = (unsigned*)d_ws;
    short* w1i = (short*)(ws + OFF_W1I);
    short* w2i = (short*)(ws + OFF_W2I);
    short* w3i = (short*)(ws + OFF_W3I);

    hipMemsetAsync(d_ws, 0, 1024, stream);

    WeightArgs wa;
    const float* srcs[12] = {w1, w2, w3, w4, w5, wl, b1, b2, b3, b4, b5, bl};
    const int    ns[12]   = {288, 18432, 1024, 2304, 1024, 640, 32, 64, 16, 16, 64, 10};
    const int    offs[12] = {OFF_W1Q, OFF_W2Q, OFF_W3Q, OFF_W4Q, OFF_W5Q, OFF_WLQ,
                             OFF_B1Q, OFF_B2Q, OFF_B3Q, OFF_B4Q, OFF_B5Q, OFF_BLQ};
    const float  mv[12]   = {127.f, 127.f, 127.f, 127.f, 127.f, 127.f,
                             32767.f, 32767.f, 32767.f, 32767.f, 32767.f, 32767.f};
    for (int i = 0; i < 12; i++) {
        wa.src[i] = srcs[i];
        wa.dst[i] = ws + offs[i];
        wa.n[i] = ns[i];
        wa.maxv[i] = mv[i];
    }
    k_weights<<<12, 256, 0, stream>>>(wa);
    k_prep_w1<<<1, 256, 0, stream>>>(w1, w1i, ws + 8);
    k_prep_w2<<<1, 256, 0, stream>>>(w2, w2i, ws + 6);
    k_prep_w3<<<1, 256, 0, stream>>>(w3, w3i, ws + 7);

    k_absmax<<<512, 256, 0, stream>>>((const float4*)x, BATCH * 256, slots + 0);
    k_s1<<<BATCH / 4, 256, 0, stream>>>(x, w1i, ws + OFF_B1Q, slots + 0, ws + 8,
                                        ws + OFF_SK1F, slots + 1);
    k_s2<<<BATCH / 4, 256, 0, stream>>>(x, w1i, ws + OFF_B1Q, w2i, ws + OFF_B2Q,
                                        ws + OFF_SK1F, slots + 0, slots + 1, ws + 8, ws + 6,
                                        ws + OFF_V2, slots + 2);
    k_s3<<<BATCH / 4, 256, 0, stream>>>(ws + OFF_V2, w3i, ws + OFF_B3Q, slots + 2, ws + 7,
                                        ws + OFF_A3, (short*)(ws + OFF_SK2I), slots + 3);
    k_conv4<<<BATCH, 256, 0, stream>>>(ws + OFF_A3, ws + OFF_W4Q, ws + OFF_B4Q, slots + 3,
                                       ws + OFF_A4, slots + 4);
    k_conv5<<<BATCH, 256, 0, stream>>>(ws + OFF_A4, ws + OFF_W5Q, ws + OFF_B5Q,
                                       (const short*)(ws + OFF_SK2I), slots + 2, slots + 4,
                                       ws + OFF_A5, slots + 5);
    k_head<<<BATCH, 64, 0, stream>>>(ws + OFF_A5, slots + 5, ws + OFF_WLQ, ws + OFF_BLQ,
                                     (float*)d_out);
}

// Round 11
// 255.674 us; speedup vs baseline: 3.0899x; 2.9108x over previous
//
#include <hip/hip_runtime.h>

#define BATCH 4096

typedef __attribute__((ext_vector_type(8))) short bf16x8;
typedef __attribute__((ext_vector_type(4))) float f32x4;

// ---------------- ws layout (floats) ----------------
// [0..15]: scalar consts ([6]=inv_sw2, [7]=inv_sw3, [8]=inv_sw1)
// [1024 + k*1024], k=0..5: spread max arrays (64 slots x 16 uints, one 64B line per slot)
//   k: 0=xmax 1=m1 2=m2 3=m3 4=m4 5=m5
constexpr int OFF_MAXARR = 1024;
constexpr int OFF_W1Q = 8192;
constexpr int OFF_W2Q = OFF_W1Q + 288;
constexpr int OFF_W3Q = OFF_W2Q + 18432;
constexpr int OFF_W4Q = OFF_W3Q + 1024;
constexpr int OFF_W5Q = OFF_W4Q + 2304;
constexpr int OFF_WLQ = OFF_W5Q + 1024;
constexpr int OFF_B1Q = OFF_WLQ + 640;
constexpr int OFF_B2Q = OFF_B1Q + 32;
constexpr int OFF_B3Q = OFF_B2Q + 64;
constexpr int OFF_B4Q = OFF_B3Q + 16;
constexpr int OFF_B5Q = OFF_B4Q + 16;
constexpr int OFF_BLQ = OFF_B5Q + 64;
constexpr int OFF_W1I = 32768;                       // 1024 shorts = 512 fl
constexpr int OFF_W2I = OFF_W1I + 512;               // 18432 shorts = 9216 fl
constexpr int OFF_W3I = OFF_W2I + 9216;              // 1024 shorts = 512 fl
constexpr size_t OFF_SK1F = 49152;                               // B*64 f32
constexpr size_t OFF_V2   = OFF_SK1F + (size_t)BATCH * 64;       // B*4096 f32
constexpr size_t OFF_SK2I = OFF_V2 + (size_t)BATCH * 4096;       // B*1024 shorts (B*512 fl)
constexpr size_t OFF_A3   = OFF_SK2I + (size_t)BATCH * 512;      // B*1024 f32
constexpr size_t OFF_A4   = OFF_A3 + (size_t)BATCH * 1024;       // B*256 f32
constexpr size_t OFF_A5   = OFF_A4 + (size_t)BATCH * 256;        // B*1024 f32
constexpr size_t WS_FLOATS_NEEDED = OFF_A5 + (size_t)BATCH * 1024;

#define A1_S   40            // a1 LDS tile ic-stride in shorts (80B)
#define A1_ROW (18 * A1_S)

// ---------------- helpers ----------------
__device__ __forceinline__ float fq(float x, float scale, float maxv) {
    float q = rintf(x * scale);                 // round-half-even == jnp.round
    q = fminf(fmaxf(q, -maxv), maxv);
    return q / scale;
}

__device__ __forceinline__ short int_to_bf16_bits(float v) {   // exact for small ints
    return (short)(__float_as_uint(v) >> 16);
}

__device__ __forceinline__ float bf16_bits_to_float(short b) {
    return __uint_as_float(((unsigned)(unsigned short)b) << 16);
}

// producer: block-reduce max (shfl + 4-wave LDS), ONE atomic per block into
// slot (blockIdx&63), each slot on its own 64B line -> no line bouncing
__device__ __forceinline__ void block_max_spread(float v, unsigned* arr, float* red4) {
#pragma unroll
    for (int off = 32; off; off >>= 1) v = fmaxf(v, __shfl_xor(v, off, 64));
    int tid = threadIdx.x;
    if ((tid & 63) == 0) red4[tid >> 6] = v;
    __syncthreads();
    if (tid == 0) {
        float m = fmaxf(fmaxf(red4[0], red4[1]), fmaxf(red4[2], red4[3]));
        atomicMax(&arr[(blockIdx.x & 63) << 4], __float_as_uint(m));
    }
    __syncthreads();
}

// consumer: reduce the 64 spread slots (L2-hot), broadcast via LDS
__device__ __forceinline__ float load_spread_max(const unsigned* arr, float* bc) {
    int tid = threadIdx.x;
    if (tid < 64) {
        float v = __uint_as_float(arr[tid << 4]);
#pragma unroll
        for (int off = 32; off; off >>= 1) v = fmaxf(v, __shfl_xor(v, off, 64));
        if (tid == 0) *bc = v;
    }
    __syncthreads();
    return *bc;
}

// stage integer-level q_x tile (bf16 bits), halo pre-zeroed
__device__ __forceinline__ void stage_xq(const float* xi, float sx, short* xt_q, int tid) {
    for (int i = tid; i < 1024; i += 256) {
        int ih = i >> 5, iw = i & 31;
        float q = rintf(xi[i] * sx);
        q = fminf(fmaxf(q, -127.f), 127.f);
        xt_q[(ih + 1) * 34 + (iw + 1)] = int_to_bf16_bits(q);
    }
}

// build A-tile qx1[pos][32]: taps k=0..8 (k>=9 pre-zeroed, never overwritten)
__device__ __forceinline__ void build_qx1(const short* xt_q, short* qx1, int tid) {
    int oh = tid >> 4, ow = tid & 15;
    short* dst = qx1 + tid * 32;
#pragma unroll
    for (int kh = 0; kh < 3; kh++)
#pragma unroll
        for (int kw = 0; kw < 3; kw++)
            dst[kh * 3 + kw] = xt_q[(oh * 2 + kh) * 34 + (ow * 2 + kw)];
}

// conv1 via exact-integer MFMA: M=256 pos, N=32 oc, K=32 (9 real taps)
__device__ __forceinline__ void conv1_mfma(const short* qx1, const bf16x8 w1b[2],
                                           int lane, int wv, f32x4 acc[4][2]) {
#pragma unroll
    for (int mb = 0; mb < 4; mb++) {
        bf16x8 a = *(const bf16x8*)(qx1 + ((wv * 4 + mb) * 16 + (lane & 15)) * 32
                                    + (lane >> 4) * 8);
#pragma unroll
        for (int nb = 0; nb < 2; nb++)
            acc[mb][nb] = __builtin_amdgcn_mfma_f32_16x16x32_bf16(a, w1b[nb], acc[mb][nb], 0, 0, 0);
    }
}

// ---------------- weight fake-quant (12 tensors, one block each) ----------------
struct WeightArgs {
    const float* src[12];
    float*       dst[12];
    int          n[12];
    float        maxv[12];
};

__global__ __launch_bounds__(256) void k_weights(WeightArgs a) {
    int t = blockIdx.x;
    const float* s = a.src[t];
    float* d = a.dst[t];
    int n = a.n[t];
    float maxv = a.maxv[t];
    __shared__ float red[256];
    int tid = threadIdx.x;
    float m = 0.f;
    for (int i = tid; i < n; i += 256) m = fmaxf(m, fabsf(s[i]));
    red[tid] = m;
    __syncthreads();
    for (int sft = 128; sft > 0; sft >>= 1) {
        if (tid < sft) red[tid] = fmaxf(red[tid], red[tid + sft]);
        __syncthreads();
    }
    float scale = maxv / red[0];
    for (int i = tid; i < n; i += 256) {
        float q = rintf(s[i] * scale);
        q = fminf(fmaxf(q, -maxv), maxv);
        d[i] = q / scale;
    }
}

// w1 [32][9] -> int-level bf16 w1i[oc][32] (taps 0..8, rest 0); inv scale -> slot
__global__ __launch_bounds__(256) void k_prep_w1(const float* __restrict__ w1,
                                                 short* __restrict__ w1i,
                                                 float* __restrict__ inv_sw_slot) {
    __shared__ float red[256];
    int tid = threadIdx.x;
    float m = 0.f;
    for (int i = tid; i < 288; i += 256) m = fmaxf(m, fabsf(w1[i]));
    red[tid] = m;
    __syncthreads();
    for (int s = 128; s > 0; s >>= 1) {
        if (tid < s) red[tid] = fmaxf(red[tid], red[tid + s]);
        __syncthreads();
    }
    float maxw = red[0];
    float sw = 127.f / maxw;
    if (tid == 0) *inv_sw_slot = maxw / 127.f;
    for (int i = tid; i < 1024; i += 256) w1i[i] = 0;
    __syncthreads();
    for (int i = tid; i < 288; i += 256) {
        int oc = i / 9, t = i % 9;
        float q = rintf(w1[i] * sw);
        q = fminf(fmaxf(q, -127.f), 127.f);
        w1i[oc * 32 + t] = int_to_bf16_bits(q);
    }
}

__global__ __launch_bounds__(256) void k_prep_w2(const float* __restrict__ w2,
                                                 short* __restrict__ w2i,
                                                 float* __restrict__ inv_sw_slot) {
    __shared__ float red[256];
    int tid = threadIdx.x;
    float m = 0.f;
    for (int i = tid; i < 18432; i += 256) m = fmaxf(m, fabsf(w2[i]));
    red[tid] = m;
    __syncthreads();
    for (int s = 128; s > 0; s >>= 1) {
        if (tid < s) red[tid] = fmaxf(red[tid], red[tid + s]);
        __syncthreads();
    }
    float maxw = red[0];
    float sw = 127.f / maxw;
    if (tid == 0) *inv_sw_slot = maxw / 127.f;
    for (int i = tid; i < 18432; i += 256) {
        int oc = i / 288, r = i % 288, ic = r / 9, t = r % 9;
        float q = rintf(w2[i] * sw);
        q = fminf(fmaxf(q, -127.f), 127.f);
        w2i[oc * 288 + t * 32 + ic] = int_to_bf16_bits(q);
    }
}

__global__ __launch_bounds__(256) void k_prep_w3(const float* __restrict__ w3,
                                                 short* __restrict__ w3i,
                                                 float* __restrict__ inv_sw_slot) {
    __shared__ float red[256];
    int tid = threadIdx.x;
    float m = 0.f;
    for (int i = tid; i < 1024; i += 256) m = fmaxf(m, fabsf(w3[i]));
    red[tid] = m;
    __syncthreads();
    for (int s = 128; s > 0; s >>= 1) {
        if (tid < s) red[tid] = fmaxf(red[tid], red[tid + s]);
        __syncthreads();
    }
    float maxw = red[0];
    float sw = 127.f / maxw;
    if (tid == 0) *inv_sw_slot = maxw / 127.f;
    for (int i = tid; i < 1024; i += 256) {
        float q = rintf(w3[i] * sw);
        q = fminf(fmaxf(q, -127.f), 127.f);
        w3i[i] = int_to_bf16_bits(q);
    }
}

// ---------------- global abs-max over x ----------------
__global__ __launch_bounds__(256) void k_absmax(const float4* __restrict__ x, int n4,
                                                unsigned* arr) {
    __shared__ float red4[4];
    float m = 0.f;
    for (int i = blockIdx.x * 256 + threadIdx.x; i < n4; i += gridDim.x * 256) {
        float4 v = x[i];
        m = fmaxf(m, fmaxf(fmaxf(fabsf(v.x), fabsf(v.y)), fmaxf(fabsf(v.z), fabsf(v.w))));
    }
    block_max_spread(m, arr, red4);
}

// ---------------- s1: conv1 (MFMA) -> m1; skip1 -> fp32 ----------------
__global__ __launch_bounds__(256) void k_s1(const float* __restrict__ x,
                                            const short* __restrict__ w1i,
                                            const float* __restrict__ b1q,
                                            const unsigned* xmaxarr,
                                            const float* __restrict__ inv_sw1p,
                                            float* __restrict__ skip1f,
                                            unsigned* m1arr) {
    __shared__ short xt_q[34 * 34];
    __shared__ short qx1[256 * 32];
    __shared__ float red4[4];
    __shared__ float bc0;
    int tid = threadIdx.x, lane = tid & 63, wv = tid >> 6;
    float xmax = load_spread_max(xmaxarr, &bc0);
    float sx = 127.f / xmax;
    float inv1 = (*inv_sw1p) / sx;
    bf16x8 w1b[2];
#pragma unroll
    for (int nb = 0; nb < 2; nb++)
        w1b[nb] = *(const bf16x8*)(w1i + (nb * 16 + (lane & 15)) * 32 + (lane >> 4) * 8);
    float bias1[2] = {b1q[lane & 15], b1q[16 + (lane & 15)]};

    for (int i = tid; i < 34 * 34; i += 256) xt_q[i] = 0;
    for (int i = tid; i < 256 * 16; i += 256) ((int*)qx1)[i] = 0;

    float lmax = 0.f;
    for (int li = 0; li < 4; li++) {
        int img = blockIdx.x * 4 + li;
        __syncthreads();
        stage_xq(x + (size_t)img * 1024, sx, xt_q, tid);
        __syncthreads();
        build_qx1(xt_q, qx1, tid);
        if (tid < 64) {           // skip1 = q_pool/sx (monotone; exact division)
            int soh = tid >> 3, sow = tid & 7;
            float m = -INFINITY;
            int h0 = soh * 4 - 2, w0 = sow * 4 - 2;
            for (int kh = 0; kh < 5; kh++) {
                int ih = h0 + kh;
                if (ih < 0 || ih >= 32) continue;
                for (int kw = 0; kw < 5; kw++) {
                    int iw = w0 + kw;
                    if (iw < 0 || iw >= 32) continue;
                    m = fmaxf(m, bf16_bits_to_float(xt_q[(ih + 1) * 34 + (iw + 1)]));
                }
            }
            skip1f[img * 64 + tid] = m / sx;
        }
        __syncthreads();
        f32x4 acc[4][2] = {};
        conv1_mfma(qx1, w1b, lane, wv, acc);
#pragma unroll
        for (int mb = 0; mb < 4; mb++)
#pragma unroll
            for (int nb = 0; nb < 2; nb++)
#pragma unroll
                for (int r = 0; r < 4; r++) {
                    float v = acc[mb][nb][r] * inv1 + bias1[nb];
                    lmax = fmaxf(lmax, fminf(fmaxf(v, 0.f), 10.f));
                }
    }
    block_max_spread(lmax, m1arr, red4);
}

// ---------------- s2: conv1 (MFMA) -> quant a1 -> conv2 (MFMA) + skip1 -> v2, m2 ----------------
__global__ __launch_bounds__(256) void k_s2(const float* __restrict__ x,
                                            const short* __restrict__ w1i,
                                            const float* __restrict__ b1q,
                                            const short* __restrict__ w2i,
                                            const float* __restrict__ b2q,
                                            const float* __restrict__ skip1f,
                                            const unsigned* xmaxarr, const unsigned* m1arr,
                                            const float* __restrict__ inv_sw1p,
                                            const float* __restrict__ inv_sw2p,
                                            float* __restrict__ v2w,
                                            unsigned* m2arr) {
    __shared__ short xt_q[34 * 34];
    __shared__ short qx1[256 * 32];
    __shared__ short a1t[18 * A1_ROW];
    __shared__ float sk1s[64];
    __shared__ float red4[4];
    __shared__ float bc0, bc1;
    int tid = threadIdx.x, lane = tid & 63, wv = tid >> 6;
    float xmax = load_spread_max(xmaxarr, &bc0);
    float m1 = load_spread_max(m1arr, &bc1);
    float sx = 127.f / xmax;
    float inv1 = (*inv_sw1p) / sx;
    float s1q = 127.f / m1;
    float inv2 = (m1 / 127.f) * (*inv_sw2p);

    bf16x8 w1b[2];
#pragma unroll
    for (int nb = 0; nb < 2; nb++)
        w1b[nb] = *(const bf16x8*)(w1i + (nb * 16 + (lane & 15)) * 32 + (lane >> 4) * 8);
    float bias1[2] = {b1q[lane & 15], b1q[16 + (lane & 15)]};
    int oc2 = wv * 16 + (lane & 15);
    bf16x8 bw2[9];
#pragma unroll
    for (int t = 0; t < 9; t++)
        bw2[t] = *(const bf16x8*)(w2i + oc2 * 288 + t * 32 + (lane >> 4) * 8);
    float bias2 = b2q[oc2];

    for (int i = tid; i < 34 * 34; i += 256) xt_q[i] = 0;
    for (int i = tid; i < 256 * 16; i += 256) ((int*)qx1)[i] = 0;
    for (int i = tid; i < 18 * A1_ROW / 2; i += 256) ((int*)a1t)[i] = 0;

    float lmax = 0.f;
    for (int li = 0; li < 4; li++) {
        int img = blockIdx.x * 4 + li;
        __syncthreads();
        stage_xq(x + (size_t)img * 1024, sx, xt_q, tid);
        if (tid < 64) sk1s[tid] = skip1f[img * 64 + tid];
        __syncthreads();
        build_qx1(xt_q, qx1, tid);
        __syncthreads();
        f32x4 acc1[4][2] = {};
        conv1_mfma(qx1, w1b, lane, wv, acc1);
        // quantize conv1 out -> a1t (identical conv1 values as s1 -> all <= m1)
#pragma unroll
        for (int mb = 0; mb < 4; mb++)
#pragma unroll
            for (int nb = 0; nb < 2; nb++)
#pragma unroll
                for (int r = 0; r < 4; r++) {
                    float v = acc1[mb][nb][r] * inv1 + bias1[nb];
                    v = fminf(fmaxf(v, 0.f), 10.f);
                    float q = fminf(rintf(v * s1q), 127.f);
                    int pos = (wv * 4 + mb) * 16 + (lane >> 4) * 4 + r;
                    int oc = nb * 16 + (lane & 15);
                    a1t[((pos >> 4) + 1) * A1_ROW + ((pos & 15) + 1) * A1_S + oc] =
                        int_to_bf16_bits(q);
                }
        __syncthreads();
        // conv2 MFMA
        float* vo = v2w + (size_t)img * 4096;
#pragma unroll
        for (int mb = 0; mb < 4; mb++) {
            int m = mb * 16 + (lane & 15);
            int oh = m >> 3, ow = m & 7;
            const short* abase = a1t + (oh * 2) * A1_ROW + (ow * 2) * A1_S + (lane >> 4) * 8;
            f32x4 acc = {0.f, 0.f, 0.f, 0.f};
#pragma unroll
            for (int kh = 0; kh < 3; kh++)
#pragma unroll
                for (int kw = 0; kw < 3; kw++) {
                    bf16x8 av = *(const bf16x8*)(abase + kh * A1_ROW + kw * A1_S);
                    acc = __builtin_amdgcn_mfma_f32_16x16x32_bf16(av, bw2[kh * 3 + kw], acc, 0, 0, 0);
                }
            float4 vv;
            float* vvp = (float*)&vv;
#pragma unroll
            for (int r = 0; r < 4; r++) {
                int pos = mb * 16 + (lane >> 4) * 4 + r;
                float v = acc[r] * inv2 + bias2 + sk1s[pos];
                v = fminf(fmaxf(v, 0.f), 10.f);
                vvp[r] = v;
                lmax = fmaxf(lmax, v);
            }
            *(float4*)(vo + oc2 * 64 + mb * 16 + (lane >> 4) * 4) = vv;
        }
    }
    block_max_spread(lmax, m2arr, red4);
}

// ---------------- s3: requant v2 -> conv3 (MFMA) -> a3, skip2 -> m3 ----------------
__global__ __launch_bounds__(256) void k_s3(const float* __restrict__ v2w,
                                            const short* __restrict__ w3i,
                                            const float* __restrict__ b3q,
                                            const unsigned* m2arr,
                                            const float* __restrict__ inv_sw3p,
                                            float* __restrict__ a3w,
                                            short* __restrict__ sk2q,
                                            unsigned* m3arr) {
    __shared__ short a2q[64 * 64];
    __shared__ float red4[4];
    __shared__ float bc0;
    int tid = threadIdx.x, lane = tid & 63, wv = tid >> 6;
    float m2 = load_spread_max(m2arr, &bc0);
    float s2 = 127.f / m2;
    float inv3 = (m2 / 127.f) * (*inv_sw3p);
    int oc2 = wv * 16 + (lane & 15);
    bf16x8 bw3[2];
#pragma unroll
    for (int t = 0; t < 2; t++)
        bw3[t] = *(const bf16x8*)(w3i + (lane & 15) * 64 + t * 32 + (lane >> 4) * 8);
    float bias3 = b3q[lane & 15];

    float lmax = 0.f;
    for (int li = 0; li < 4; li++) {
        int img = blockIdx.x * 4 + li;
        __syncthreads();
        const float* vi = v2w + (size_t)img * 4096;
#pragma unroll
        for (int mb = 0; mb < 4; mb++) {
            float4 vv = *(const float4*)(vi + oc2 * 64 + mb * 16 + (lane >> 4) * 4);
            const float* vvp = (const float*)&vv;
#pragma unroll
            for (int r = 0; r < 4; r++) {
                int pos = mb * 16 + (lane >> 4) * 4 + r;
                float q = fminf(rintf(vvp[r] * s2), 127.f);
                a2q[pos * 64 + oc2] = int_to_bf16_bits(q);
            }
        }
        __syncthreads();
        const short* abase = a2q + (wv * 16 + (lane & 15)) * 64 + (lane >> 4) * 8;
        f32x4 acc = {0.f, 0.f, 0.f, 0.f};
#pragma unroll
        for (int t = 0; t < 2; t++) {
            bf16x8 av = *(const bf16x8*)(abase + t * 32);
            acc = __builtin_amdgcn_mfma_f32_16x16x32_bf16(av, bw3[t], acc, 0, 0, 0);
        }
        float* a3o = a3w + (size_t)img * 1024;
#pragma unroll
        for (int r = 0; r < 4; r++) {
            int pos = wv * 16 + (lane >> 4) * 4 + r;
            float v = acc[r] * inv3 + bias3;
            v = fminf(fmaxf(v, 0.f), 10.f);
            a3o[(lane & 15) * 64 + pos] = v;
            lmax = fmaxf(lmax, v);
        }
        // skip2 = pool(q2,3,2,1) int bf16 (scale applied at conv5)
        short* sko = sk2q + (size_t)img * 1024;
#pragma unroll
        for (int r = 0; r < 4; ++r) {
            int idx = tid * 4 + r;
            int c = idx >> 4, pp = idx & 15, soh = pp >> 2, sow = pp & 3;
            float m = -INFINITY;
            for (int kh = 0; kh < 3; kh++) {
                int ih = soh * 2 - 1 + kh;
                if (ih < 0 || ih >= 8) continue;
                for (int kw = 0; kw < 3; kw++) {
                    int iw = sow * 2 - 1 + kw;
                    if (iw < 0 || iw >= 8) continue;
                    m = fmaxf(m, bf16_bits_to_float(a2q[(ih * 8 + iw) * 64 + c]));
                }
            }
            sko[idx] = int_to_bf16_bits(m);
        }
    }
    block_max_spread(lmax, m3arr, red4);
}

// ---------------- conv4: 3x3, s2 p1, 16->16, 8x8->4x4, clip ----------------
__global__ __launch_bounds__(256) void k_conv4(const float* __restrict__ a3,
                                               const float* __restrict__ w4q,
                                               const float* __restrict__ b4q,
                                               const unsigned* m3arr,
                                               float* __restrict__ a4,
                                               unsigned* m4arr) {
    __shared__ float tile[16 * 10 * 10];
    __shared__ float red4[4];
    __shared__ float bc0;
    int b = blockIdx.x, tid = threadIdx.x;
    float m3 = load_spread_max(m3arr, &bc0);
    float s3 = 127.f / m3;
    for (int i = tid; i < 1600; i += 256) tile[i] = 0.f;
    __syncthreads();
    const float* ai = a3 + (size_t)b * 1024;
    for (int i = tid; i < 1024; i += 256) {
        int ic = i >> 6, p = i & 63, ih = p >> 3, iw = p & 7;
        float q = rintf(ai[i] * s3);
        q = fminf(fmaxf(q, -127.f), 127.f);
        tile[ic * 100 + (ih + 1) * 10 + (iw + 1)] = q / s3;
    }
    __syncthreads();
    int oc = tid >> 4, p = tid & 15, oh = p >> 2, ow = p & 3;
    float acc = b4q[oc];
    const float* w = w4q + oc * 144;
    for (int ic = 0; ic < 16; ic++) {
        const float* tin = tile + ic * 100 + (oh * 2) * 10 + (ow * 2);
        const float* wc = w + ic * 9;
#pragma unroll
        for (int kh = 0; kh < 3; kh++)
#pragma unroll
            for (int kw = 0; kw < 3; kw++)
                acc += tin[kh * 10 + kw] * wc[kh * 3 + kw];
    }
    float v = fminf(fmaxf(acc, 0.f), 10.f);
    a4[(size_t)b * 256 + tid] = v;
    block_max_spread(v, m4arr, red4);
}

// ---------------- conv5: 1x1, 16->64 on 4x4, +skip2, clip ----------------
__global__ __launch_bounds__(256) void k_conv5(const float* __restrict__ a4,
                                               const float* __restrict__ w5q,
                                               const float* __restrict__ b5q,
                                               const short* __restrict__ sk2q,
                                               const unsigned* m2arr,
                                               const unsigned* m4arr,
                                               float* __restrict__ a5,
                                               unsigned* m5arr) {
    __shared__ float tin[256];
    __shared__ float red4[4];
    __shared__ float bc0, bc1;
    int b = blockIdx.x, tid = threadIdx.x;
    float m2 = load_spread_max(m2arr, &bc0);
    float m4 = load_spread_max(m4arr, &bc1);
    float s4 = 127.f / m4;
    float invs2 = m2 / 127.f;
    const float* ai = a4 + (size_t)b * 256;
    {
        float q = rintf(ai[tid] * s4);
        q = fminf(fmaxf(q, -127.f), 127.f);
        tin[tid] = q / s4;
    }
    __syncthreads();
    int p = tid & 15, ocb = tid >> 4;
    float lmax = 0.f;
    float* o = a5 + (size_t)b * 1024;
    for (int j = 0; j < 4; j++) {
        int oc = ocb * 4 + j;
        float acc = b5q[oc];
        const float* w = w5q + oc * 16;
#pragma unroll
        for (int ic = 0; ic < 16; ic++) acc += tin[ic * 16 + p] * w[ic];
        acc += bf16_bits_to_float(sk2q[(size_t)b * 1024 + oc * 16 + p]) * invs2;
        float v = fminf(fmaxf(acc, 0.f), 10.f);
        o[oc * 16 + p] = v;
        lmax = fmaxf(lmax, v);
    }
    block_max_spread(lmax, m5arr, red4);
}

// ---------------- head: fq(a5) -> mean(4x4) -> linear ----------------
__global__ __launch_bounds__(64) void k_head(const float* __restrict__ a5,
                                             const unsigned* m5arr,
                                             const float* __restrict__ wlq,
                                             const float* __restrict__ blq,
                                             float* __restrict__ out) {
    __shared__ float h[64];
    __shared__ float bc0;
    int b = blockIdx.x, c = threadIdx.x;
    float m5 = load_spread_max(m5arr, &bc0);
    float s5 = 127.f / m5;
    const float* ai = a5 + (size_t)b * 1024 + c * 16;
    float sum = 0.f;
#pragma unroll
    for (int p = 0; p < 16; p++) sum += fq(ai[p], s5, 127.f);
    h[c] = sum * (1.f / 16.f);
    __syncthreads();
    if (c < 10) {
        float acc = blq[c];
        const float* w = wlq + c * 64;
        for (int ic = 0; ic < 64; ic++) acc = fmaf(h[ic], w[ic], acc);
        out[(size_t)b * 10 + c] = acc;
    }
}

// ---------------- launch ----------------
extern "C" void kernel_launch(void* const* d_in, const int* in_sizes, int n_in,
                              void* d_out, int out_size, void* d_ws, size_t ws_size,
                              hipStream_t stream) {
    const float* x  = (const float*)d_in[0];
    const float* w1 = (const float*)d_in[1];
    const float* b1 = (const float*)d_in[2];
    const float* w2 = (const float*)d_in[3];
    const float* b2 = (const float*)d_in[4];
    const float* w3 = (const float*)d_in[5];
    const float* b3 = (const float*)d_in[6];
    const float* w4 = (const float*)d_in[7];
    const float* b4 = (const float*)d_in[8];
    const float* w5 = (const float*)d_in[9];
    const float* b5 = (const float*)d_in[10];
    const float* wl = (const float*)d_in[11];
    const float* bl = (const float*)d_in[12];

    if (ws_size < WS_FLOATS_NEEDED * sizeof(float)) return;

    float* ws = (float*)d_ws;
    unsigned* slots = (unsigned*)d_ws;
    unsigned* marr[6];
    for (int k = 0; k < 6; k++) marr[k] = slots + OFF_MAXARR + k * 1024;
    short* w1i = (short*)(ws + OFF_W1I);
    short* w2i = (short*)(ws + OFF_W2I);
    short* w3i = (short*)(ws + OFF_W3I);

    hipMemsetAsync(d_ws, 0, 32768, stream);   // scalar consts + 6 spread-max arrays

    WeightArgs wa;
    const float* srcs[12] = {w1, w2, w3, w4, w5, wl, b1, b2, b3, b4, b5, bl};
    const int    ns[12]   = {288, 18432, 1024, 2304, 1024, 640, 32, 64, 16, 16, 64, 10};
    const int    offs[12] = {OFF_W1Q, OFF_W2Q, OFF_W3Q, OFF_W4Q, OFF_W5Q, OFF_WLQ,
                             OFF_B1Q, OFF_B2Q, OFF_B3Q, OFF_B4Q, OFF_B5Q, OFF_BLQ};
    const float  mv[12]   = {127.f, 127.f, 127.f, 127.f, 127.f, 127.f,
                             32767.f, 32767.f, 32767.f, 32767.f, 32767.f, 32767.f};
    for (int i = 0; i < 12; i++) {
        wa.src[i] = srcs[i];
        wa.dst[i] = ws + offs[i];
        wa.n[i] = ns[i];
        wa.maxv[i] = mv[i];
    }
    k_weights<<<12, 256, 0, stream>>>(wa);
    k_prep_w1<<<1, 256, 0, stream>>>(w1, w1i, ws + 8);
    k_prep_w2<<<1, 256, 0, stream>>>(w2, w2i, ws + 6);
    k_prep_w3<<<1, 256, 0, stream>>>(w3, w3i, ws + 7);

    k_absmax<<<512, 256, 0, stream>>>((const float4*)x, BATCH * 256, marr[0]);
    k_s1<<<BATCH / 4, 256, 0, stream>>>(x, w1i, ws + OFF_B1Q, marr[0], ws + 8,
                                        ws + OFF_SK1F, marr[1]);
    k_s2<<<BATCH / 4, 256, 0, stream>>>(x, w1i, ws + OFF_B1Q, w2i, ws + OFF_B2Q,
                                        ws + OFF_SK1F, marr[0], marr[1], ws + 8, ws + 6,
                                        ws + OFF_V2, marr[2]);
    k_s3<<<BATCH / 4, 256, 0, stream>>>(ws + OFF_V2, w3i, ws + OFF_B3Q, marr[2], ws + 7,
                                        ws + OFF_A3, (short*)(ws + OFF_SK2I), marr[3]);
    k_conv4<<<BATCH, 256, 0, stream>>>(ws + OFF_A3, ws + OFF_W4Q, ws + OFF_B4Q, marr[3],
                                       ws + OFF_A4, marr[4]);
    k_conv5<<<BATCH, 256, 0, stream>>>(ws + OFF_A4, ws + OFF_W5Q, ws + OFF_B5Q,
                                       (const short*)(ws + OFF_SK2I), marr[2], marr[4],
                                       ws + OFF_A5, marr[5]);
    k_head<<<BATCH, 64, 0, stream>>>(ws + OFF_A5, marr[5], ws + OFF_WLQ, ws + OFF_BLQ,
                                     (float*)d_out);
}

// Round 12
// 210.610 us; speedup vs baseline: 3.7510x; 1.2140x over previous
//
#include <hip/hip_runtime.h>

#define BATCH 4096

typedef __attribute__((ext_vector_type(8))) short bf16x8;
typedef __attribute__((ext_vector_type(4))) float f32x4;

// ---------------- ws layout (floats) ----------------
// [0..15]: scalar consts ([6]=inv_sw2, [7]=inv_sw3, [8]=inv_sw1)
// [1024 + k*1024], k=0..5: spread max arrays (64 slots x 16 uints, one 64B line per slot)
constexpr int OFF_MAXARR = 1024;
constexpr int OFF_W1Q = 8192;
constexpr int OFF_W2Q = OFF_W1Q + 288;
constexpr int OFF_W3Q = OFF_W2Q + 18432;
constexpr int OFF_W4Q = OFF_W3Q + 1024;
constexpr int OFF_W5Q = OFF_W4Q + 2304;
constexpr int OFF_WLQ = OFF_W5Q + 1024;
constexpr int OFF_B1Q = OFF_WLQ + 640;
constexpr int OFF_B2Q = OFF_B1Q + 32;
constexpr int OFF_B3Q = OFF_B2Q + 64;
constexpr int OFF_B4Q = OFF_B3Q + 16;
constexpr int OFF_B5Q = OFF_B4Q + 16;
constexpr int OFF_BLQ = OFF_B5Q + 64;
constexpr int OFF_W1I = 32768;                       // 1024 shorts = 512 fl
constexpr int OFF_W2I = OFF_W1I + 512;               // 18432 shorts = 9216 fl
constexpr int OFF_W3I = OFF_W2I + 9216;              // 1024 shorts = 512 fl
constexpr size_t OFF_SK1F = 49152;                               // B*64 f32
constexpr size_t OFF_V2   = OFF_SK1F + (size_t)BATCH * 64;       // B*4096 f32
constexpr size_t OFF_SK2I = OFF_V2 + (size_t)BATCH * 4096;       // B*1024 shorts
constexpr size_t OFF_A3   = OFF_SK2I + (size_t)BATCH * 512;      // B*1024 f32
constexpr size_t OFF_A4   = OFF_A3 + (size_t)BATCH * 1024;       // B*256 f32
constexpr size_t OFF_A5   = OFF_A4 + (size_t)BATCH * 256;        // B*1024 f32
constexpr size_t WS_FLOATS_NEEDED = OFF_A5 + (size_t)BATCH * 1024;

#define A1_S   40            // a1 LDS tile ic-stride in shorts (80B)
#define A1_ROW (18 * A1_S)

// ---------------- helpers ----------------
__device__ __forceinline__ float fq(float x, float scale, float maxv) {
    float q = rintf(x * scale);                 // round-half-even == jnp.round
    q = fminf(fmaxf(q, -maxv), maxv);
    return q / scale;
}

__device__ __forceinline__ short int_to_bf16_bits(float v) {   // exact for small ints
    return (short)(__float_as_uint(v) >> 16);
}

__device__ __forceinline__ float bf16_bits_to_float(short b) {
    return __uint_as_float(((unsigned)(unsigned short)b) << 16);
}

// producer: block-reduce max, ONE atomic per block into slot (blockIdx&63)
__device__ __forceinline__ void block_max_spread(float v, unsigned* arr, float* red4) {
#pragma unroll
    for (int off = 32; off; off >>= 1) v = fmaxf(v, __shfl_xor(v, off, 64));
    int tid = threadIdx.x;
    if ((tid & 63) == 0) red4[tid >> 6] = v;
    __syncthreads();
    if (tid == 0) {
        float m = fmaxf(fmaxf(red4[0], red4[1]), fmaxf(red4[2], red4[3]));
        atomicMax(&arr[(blockIdx.x & 63) << 4], __float_as_uint(m));
    }
    __syncthreads();
}

// consumer: reduce the 64 spread slots (L2-hot), broadcast via LDS
__device__ __forceinline__ float load_spread_max(const unsigned* arr, float* bc) {
    int tid = threadIdx.x;
    if (tid < 64) {
        float v = __uint_as_float(arr[tid << 4]);
#pragma unroll
        for (int off = 32; off; off >>= 1) v = fmaxf(v, __shfl_xor(v, off, 64));
        if (tid == 0) *bc = v;
    }
    __syncthreads();
    return *bc;
}

// stage integer-level q_x tile (bf16 bits), halo pre-zeroed
__device__ __forceinline__ void stage_xq(const float* xi, float sx, short* xt_q, int tid) {
    for (int i = tid; i < 1024; i += 256) {
        int ih = i >> 5, iw = i & 31;
        float q = rintf(xi[i] * sx);
        q = fminf(fmaxf(q, -127.f), 127.f);
        xt_q[(ih + 1) * 34 + (iw + 1)] = int_to_bf16_bits(q);
    }
}

// direct A-fragment load from xt_q (no qx1 staging): values identical to the
// old qx1[pos][k] path -> MFMA results bitwise unchanged
__device__ __forceinline__ bf16x8 load_a1frag(const short* xt_q, int pos, int kslot) {
    bf16x8 a = {0, 0, 0, 0, 0, 0, 0, 0};
    int oh = pos >> 4, ow = pos & 15;
    const short* base = xt_q + (oh * 2) * 34 + ow * 2;
    if (kslot == 0) {           // taps 0..7
        a[0] = base[0];  a[1] = base[1];  a[2] = base[2];
        a[3] = base[34]; a[4] = base[35]; a[5] = base[36];
        a[6] = base[68]; a[7] = base[69];
    } else if (kslot == 1) {    // tap 8, rest zero
        a[0] = base[70];
    }
    return a;
}

// ---------------- fused prep: 12 weight fakequants + w1i/w2i/w3i + absmax(x) ----------------
struct PrepArgs {
    const float* src[12];
    float*       dst[12];
    int          n[12];
    float        maxv[12];
    const float* w1; short* w1i; float* inv1;
    const float* w2; short* w2i; float* inv2;
    const float* w3; short* w3i; float* inv3;
    const float4* x; int n4; unsigned* xarr;
};

__global__ __launch_bounds__(256) void k_prep(PrepArgs P) {
    __shared__ float red[256];
    __shared__ float red4[4];
    int b = blockIdx.x, tid = threadIdx.x;
    if (b < 12) {
        const float* s = P.src[b];
        float* d = P.dst[b];
        int n = P.n[b];
        float maxv = P.maxv[b];
        float m = 0.f;
        for (int i = tid; i < n; i += 256) m = fmaxf(m, fabsf(s[i]));
        red[tid] = m;
        __syncthreads();
        for (int sft = 128; sft > 0; sft >>= 1) {
            if (tid < sft) red[tid] = fmaxf(red[tid], red[tid + sft]);
            __syncthreads();
        }
        float scale = maxv / red[0];
        for (int i = tid; i < n; i += 256) {
            float q = rintf(s[i] * scale);
            q = fminf(fmaxf(q, -maxv), maxv);
            d[i] = q / scale;
        }
    } else if (b == 12) {       // w1 -> int-level bf16 [oc][32] (taps 0..8, rest 0)
        float m = 0.f;
        for (int i = tid; i < 288; i += 256) m = fmaxf(m, fabsf(P.w1[i]));
        red[tid] = m;
        __syncthreads();
        for (int s = 128; s > 0; s >>= 1) {
            if (tid < s) red[tid] = fmaxf(red[tid], red[tid + s]);
            __syncthreads();
        }
        float maxw = red[0];
        float sw = 127.f / maxw;
        if (tid == 0) *P.inv1 = maxw / 127.f;
        for (int i = tid; i < 1024; i += 256) P.w1i[i] = 0;
        __syncthreads();
        for (int i = tid; i < 288; i += 256) {
            int oc = i / 9, t = i % 9;
            float q = rintf(P.w1[i] * sw);
            q = fminf(fmaxf(q, -127.f), 127.f);
            P.w1i[oc * 32 + t] = int_to_bf16_bits(q);
        }
    } else if (b == 13) {       // w2 -> [oc][t*32+ic]
        float m = 0.f;
        for (int i = tid; i < 18432; i += 256) m = fmaxf(m, fabsf(P.w2[i]));
        red[tid] = m;
        __syncthreads();
        for (int s = 128; s > 0; s >>= 1) {
            if (tid < s) red[tid] = fmaxf(red[tid], red[tid + s]);
            __syncthreads();
        }
        float maxw = red[0];
        float sw = 127.f / maxw;
        if (tid == 0) *P.inv2 = maxw / 127.f;
        for (int i = tid; i < 18432; i += 256) {
            int oc = i / 288, r = i % 288, ic = r / 9, t = r % 9;
            float q = rintf(P.w2[i] * sw);
            q = fminf(fmaxf(q, -127.f), 127.f);
            P.w2i[oc * 288 + t * 32 + ic] = int_to_bf16_bits(q);
        }
    } else if (b == 14) {       // w3 -> [oc][ic]
        float m = 0.f;
        for (int i = tid; i < 1024; i += 256) m = fmaxf(m, fabsf(P.w3[i]));
        red[tid] = m;
        __syncthreads();
        for (int s = 128; s > 0; s >>= 1) {
            if (tid < s) red[tid] = fmaxf(red[tid], red[tid + s]);
            __syncthreads();
        }
        float maxw = red[0];
        float sw = 127.f / maxw;
        if (tid == 0) *P.inv3 = maxw / 127.f;
        for (int i = tid; i < 1024; i += 256) {
            float q = rintf(P.w3[i] * sw);
            q = fminf(fmaxf(q, -127.f), 127.f);
            P.w3i[i] = int_to_bf16_bits(q);
        }
    } else {                    // absmax(x), blocks 15..gridDim-1
        float m = 0.f;
        int nb = gridDim.x - 15;
        for (int i = (b - 15) * 256 + tid; i < P.n4; i += nb * 256) {
            float4 v = P.x[i];
            m = fmaxf(m, fmaxf(fmaxf(fabsf(v.x), fabsf(v.y)), fmaxf(fabsf(v.z), fabsf(v.w))));
        }
        block_max_spread(m, P.xarr, red4);
    }
}

// ---------------- s1: conv1 (MFMA) -> m1; skip1 -> fp32 ----------------
__global__ __launch_bounds__(256) void k_s1(const float* __restrict__ x,
                                            const short* __restrict__ w1i,
                                            const float* __restrict__ b1q,
                                            const unsigned* xmaxarr,
                                            const float* __restrict__ inv_sw1p,
                                            float* __restrict__ skip1f,
                                            unsigned* m1arr) {
    __shared__ short xt_q[34 * 34];
    __shared__ float red4[4];
    __shared__ float bc0;
    int tid = threadIdx.x, lane = tid & 63, wv = tid >> 6;
    int kslot = lane >> 4;
    float xmax = load_spread_max(xmaxarr, &bc0);
    float sx = 127.f / xmax;
    float inv1 = (*inv_sw1p) / sx;
    bf16x8 w1b[2];
#pragma unroll
    for (int nb = 0; nb < 2; nb++)
        w1b[nb] = *(const bf16x8*)(w1i + (nb * 16 + (lane & 15)) * 32 + kslot * 8);
    float bias1[2] = {b1q[lane & 15], b1q[16 + (lane & 15)]};

    for (int i = tid; i < 34 * 34; i += 256) xt_q[i] = 0;

    float lmax = 0.f;
    for (int li = 0; li < 4; li++) {
        int img = blockIdx.x * 4 + li;
        __syncthreads();
        stage_xq(x + (size_t)img * 1024, sx, xt_q, tid);
        __syncthreads();
        if (tid < 64) {           // skip1 = q_pool/sx (monotone; exact division)
            int soh = tid >> 3, sow = tid & 7;
            float m = -INFINITY;
            int h0 = soh * 4 - 2, w0 = sow * 4 - 2;
            for (int kh = 0; kh < 5; kh++) {
                int ih = h0 + kh;
                if (ih < 0 || ih >= 32) continue;
                for (int kw = 0; kw < 5; kw++) {
                    int iw = w0 + kw;
                    if (iw < 0 || iw >= 32) continue;
                    m = fmaxf(m, bf16_bits_to_float(xt_q[(ih + 1) * 34 + (iw + 1)]));
                }
            }
            skip1f[img * 64 + tid] = m / sx;
        }
        f32x4 acc[4][2] = {};
#pragma unroll
        for (int mb = 0; mb < 4; mb++) {
            bf16x8 a = load_a1frag(xt_q, (wv * 4 + mb) * 16 + (lane & 15), kslot);
#pragma unroll
            for (int nb = 0; nb < 2; nb++)
                acc[mb][nb] = __builtin_amdgcn_mfma_f32_16x16x32_bf16(a, w1b[nb], acc[mb][nb], 0, 0, 0);
        }
#pragma unroll
        for (int mb = 0; mb < 4; mb++)
#pragma unroll
            for (int nb = 0; nb < 2; nb++)
#pragma unroll
                for (int r = 0; r < 4; r++) {
                    float v = acc[mb][nb][r] * inv1 + bias1[nb];
                    lmax = fmaxf(lmax, fminf(fmaxf(v, 0.f), 10.f));
                }
    }
    block_max_spread(lmax, m1arr, red4);
}

// ---------------- s2: conv1 (MFMA) -> quant a1 -> conv2 (MFMA) + skip1 -> v2, m2 ----------------
__global__ __launch_bounds__(256) void k_s2(const float* __restrict__ x,
                                            const short* __restrict__ w1i,
                                            const float* __restrict__ b1q,
                                            const short* __restrict__ w2i,
                                            const float* __restrict__ b2q,
                                            const float* __restrict__ skip1f,
                                            const unsigned* xmaxarr, const unsigned* m1arr,
                                            const float* __restrict__ inv_sw1p,
                                            const float* __restrict__ inv_sw2p,
                                            float* __restrict__ v2w,
                                            unsigned* m2arr) {
    __shared__ short xt_q[34 * 34];
    __shared__ short a1t[18 * A1_ROW];
    __shared__ float sk1s[64];
    __shared__ float red4[4];
    __shared__ float bc0, bc1;
    int tid = threadIdx.x, lane = tid & 63, wv = tid >> 6;
    int kslot = lane >> 4;
    float xmax = load_spread_max(xmaxarr, &bc0);
    float m1 = load_spread_max(m1arr, &bc1);
    float sx = 127.f / xmax;
    float inv1 = (*inv_sw1p) / sx;
    float s1q = 127.f / m1;
    float inv2 = (m1 / 127.f) * (*inv_sw2p);

    bf16x8 w1b[2];
#pragma unroll
    for (int nb = 0; nb < 2; nb++)
        w1b[nb] = *(const bf16x8*)(w1i + (nb * 16 + (lane & 15)) * 32 + kslot * 8);
    float bias1[2] = {b1q[lane & 15], b1q[16 + (lane & 15)]};
    int oc2 = wv * 16 + (lane & 15);
    bf16x8 bw2[9];
#pragma unroll
    for (int t = 0; t < 9; t++)
        bw2[t] = *(const bf16x8*)(w2i + oc2 * 288 + t * 32 + kslot * 8);
    float bias2 = b2q[oc2];

    for (int i = tid; i < 34 * 34; i += 256) xt_q[i] = 0;
    for (int i = tid; i < 18 * A1_ROW / 2; i += 256) ((int*)a1t)[i] = 0;

    float lmax = 0.f;
    for (int li = 0; li < 4; li++) {
        int img = blockIdx.x * 4 + li;
        __syncthreads();
        stage_xq(x + (size_t)img * 1024, sx, xt_q, tid);
        if (tid < 64) sk1s[tid] = skip1f[img * 64 + tid];
        __syncthreads();
        f32x4 acc1[4][2] = {};
#pragma unroll
        for (int mb = 0; mb < 4; mb++) {
            bf16x8 a = load_a1frag(xt_q, (wv * 4 + mb) * 16 + (lane & 15), kslot);
#pragma unroll
            for (int nb = 0; nb < 2; nb++)
                acc1[mb][nb] = __builtin_amdgcn_mfma_f32_16x16x32_bf16(a, w1b[nb], acc1[mb][nb], 0, 0, 0);
        }
        // quantize conv1 out -> a1t (bitwise same conv1 values as s1 -> all <= m1)
#pragma unroll
        for (int mb = 0; mb < 4; mb++)
#pragma unroll
            for (int nb = 0; nb < 2; nb++)
#pragma unroll
                for (int r = 0; r < 4; r++) {
                    float v = acc1[mb][nb][r] * inv1 + bias1[nb];
                    v = fminf(fmaxf(v, 0.f), 10.f);
                    float q = fminf(rintf(v * s1q), 127.f);
                    int pos = (wv * 4 + mb) * 16 + (lane >> 4) * 4 + r;
                    int oc = nb * 16 + (lane & 15);
                    a1t[((pos >> 4) + 1) * A1_ROW + ((pos & 15) + 1) * A1_S + oc] =
                        int_to_bf16_bits(q);
                }
        __syncthreads();
        // conv2 MFMA
        float* vo = v2w + (size_t)img * 4096;
#pragma unroll
        for (int mb = 0; mb < 4; mb++) {
            int m = mb * 16 + (lane & 15);
            int oh = m >> 3, ow = m & 7;
            const short* abase = a1t + (oh * 2) * A1_ROW + (ow * 2) * A1_S + kslot * 8;
            f32x4 acc = {0.f, 0.f, 0.f, 0.f};
#pragma unroll
            for (int kh = 0; kh < 3; kh++)
#pragma unroll
                for (int kw = 0; kw < 3; kw++) {
                    bf16x8 av = *(const bf16x8*)(abase + kh * A1_ROW + kw * A1_S);
                    acc = __builtin_amdgcn_mfma_f32_16x16x32_bf16(av, bw2[kh * 3 + kw], acc, 0, 0, 0);
                }
            float4 vv;
            float* vvp = (float*)&vv;
#pragma unroll
            for (int r = 0; r < 4; r++) {
                int pos = mb * 16 + (lane >> 4) * 4 + r;
                float v = acc[r] * inv2 + bias2 + sk1s[pos];
                v = fminf(fmaxf(v, 0.f), 10.f);
                vvp[r] = v;
                lmax = fmaxf(lmax, v);
            }
            *(float4*)(vo + oc2 * 64 + mb * 16 + (lane >> 4) * 4) = vv;
        }
    }
    block_max_spread(lmax, m2arr, red4);
}

// ---------------- s3: requant v2 -> conv3 (MFMA) -> a3, skip2 -> m3 ----------------
__global__ __launch_bounds__(256) void k_s3(const float* __restrict__ v2w,
                                            const short* __restrict__ w3i,
                                            const float* __restrict__ b3q,
                                            const unsigned* m2arr,
                                            const float* __restrict__ inv_sw3p,
                                            float* __restrict__ a3w,
                                            short* __restrict__ sk2q,
                                            unsigned* m3arr) {
    __shared__ short a2q[64 * 64];
    __shared__ float red4[4];
    __shared__ float bc0;
    int tid = threadIdx.x, lane = tid & 63, wv = tid >> 6;
    float m2 = load_spread_max(m2arr, &bc0);
    float s2 = 127.f / m2;
    float inv3 = (m2 / 127.f) * (*inv_sw3p);
    int oc2 = wv * 16 + (lane & 15);
    bf16x8 bw3[2];
#pragma unroll
    for (int t = 0; t < 2; t++)
        bw3[t] = *(const bf16x8*)(w3i + (lane & 15) * 64 + t * 32 + (lane >> 4) * 8);
    float bias3 = b3q[lane & 15];

    float lmax = 0.f;
    for (int li = 0; li < 4; li++) {
        int img = blockIdx.x * 4 + li;
        __syncthreads();
        const float* vi = v2w + (size_t)img * 4096;
#pragma unroll
        for (int mb = 0; mb < 4; mb++) {
            float4 vv = *(const float4*)(vi + oc2 * 64 + mb * 16 + (lane >> 4) * 4);
            const float* vvp = (const float*)&vv;
#pragma unroll
            for (int r = 0; r < 4; r++) {
                int pos = mb * 16 + (lane >> 4) * 4 + r;
                float q = fminf(rintf(vvp[r] * s2), 127.f);
                a2q[pos * 64 + oc2] = int_to_bf16_bits(q);
            }
        }
        __syncthreads();
        const short* abase = a2q + (wv * 16 + (lane & 15)) * 64 + (lane >> 4) * 8;
        f32x4 acc = {0.f, 0.f, 0.f, 0.f};
#pragma unroll
        for (int t = 0; t < 2; t++) {
            bf16x8 av = *(const bf16x8*)(abase + t * 32);
            acc = __builtin_amdgcn_mfma_f32_16x16x32_bf16(av, bw3[t], acc, 0, 0, 0);
        }
        float* a3o = a3w + (size_t)img * 1024;
#pragma unroll
        for (int r = 0; r < 4; r++) {
            int pos = wv * 16 + (lane >> 4) * 4 + r;
            float v = acc[r] * inv3 + bias3;
            v = fminf(fmaxf(v, 0.f), 10.f);
            a3o[(lane & 15) * 64 + pos] = v;
            lmax = fmaxf(lmax, v);
        }
        // skip2 = pool(q2,3,2,1) int bf16 (scale applied at conv5)
        short* sko = sk2q + (size_t)img * 1024;
#pragma unroll
        for (int r = 0; r < 4; ++r) {
            int idx = tid * 4 + r;
            int c = idx >> 4, pp = idx & 15, soh = pp >> 2, sow = pp & 3;
            float m = -INFINITY;
            for (int kh = 0; kh < 3; kh++) {
                int ih = soh * 2 - 1 + kh;
                if (ih < 0 || ih >= 8) continue;
                for (int kw = 0; kw < 3; kw++) {
                    int iw = sow * 2 - 1 + kw;
                    if (iw < 0 || iw >= 8) continue;
                    m = fmaxf(m, bf16_bits_to_float(a2q[(ih * 8 + iw) * 64 + c]));
                }
            }
            sko[idx] = int_to_bf16_bits(m);
        }
    }
    block_max_spread(lmax, m3arr, red4);
}

// ---------------- conv4: 3x3, s2 p1, 16->16, 8x8->4x4, clip ----------------
__global__ __launch_bounds__(256) void k_conv4(const float* __restrict__ a3,
                                               const float* __restrict__ w4q,
                                               const float* __restrict__ b4q,
                                               const unsigned* m3arr,
                                               float* __restrict__ a4,
                                               unsigned* m4arr) {
    __shared__ float tile[16 * 10 * 10];
    __shared__ float red4[4];
    __shared__ float bc0;
    int b = blockIdx.x, tid = threadIdx.x;
    float m3 = load_spread_max(m3arr, &bc0);
    float s3 = 127.f / m3;
    for (int i = tid; i < 1600; i += 256) tile[i] = 0.f;
    __syncthreads();
    const float* ai = a3 + (size_t)b * 1024;
    for (int i = tid; i < 1024; i += 256) {
        int ic = i >> 6, p = i & 63, ih = p >> 3, iw = p & 7;
        float q = rintf(ai[i] * s3);
        q = fminf(fmaxf(q, -127.f), 127.f);
        tile[ic * 100 + (ih + 1) * 10 + (iw + 1)] = q / s3;
    }
    __syncthreads();
    int oc = tid >> 4, p = tid & 15, oh = p >> 2, ow = p & 3;
    float acc = b4q[oc];
    const float* w = w4q + oc * 144;
    for (int ic = 0; ic < 16; ic++) {
        const float* tin = tile + ic * 100 + (oh * 2) * 10 + (ow * 2);
        const float* wc = w + ic * 9;
#pragma unroll
        for (int kh = 0; kh < 3; kh++)
#pragma unroll
            for (int kw = 0; kw < 3; kw++)
                acc += tin[kh * 10 + kw] * wc[kh * 3 + kw];
    }
    float v = fminf(fmaxf(acc, 0.f), 10.f);
    a4[(size_t)b * 256 + tid] = v;
    block_max_spread(v, m4arr, red4);
}

// ---------------- conv5: 1x1, 16->64 on 4x4, +skip2, clip ----------------
__global__ __launch_bounds__(256) void k_conv5(const float* __restrict__ a4,
                                               const float* __restrict__ w5q,
                                               const float* __restrict__ b5q,
                                               const short* __restrict__ sk2q,
                                               const unsigned* m2arr,
                                               const unsigned* m4arr,
                                               float* __restrict__ a5,
                                               unsigned* m5arr) {
    __shared__ float tin[256];
    __shared__ float red4[4];
    __shared__ float bc0, bc1;
    int b = blockIdx.x, tid = threadIdx.x;
    float m2 = load_spread_max(m2arr, &bc0);
    float m4 = load_spread_max(m4arr, &bc1);
    float s4 = 127.f / m4;
    float invs2 = m2 / 127.f;
    const float* ai = a4 + (size_t)b * 256;
    {
        float q = rintf(ai[tid] * s4);
        q = fminf(fmaxf(q, -127.f), 127.f);
        tin[tid] = q / s4;
    }
    __syncthreads();
    int p = tid & 15, ocb = tid >> 4;
    float lmax = 0.f;
    float* o = a5 + (size_t)b * 1024;
    for (int j = 0; j < 4; j++) {
        int oc = ocb * 4 + j;
        float acc = b5q[oc];
        const float* w = w5q + oc * 16;
#pragma unroll
        for (int ic = 0; ic < 16; ic++) acc += tin[ic * 16 + p] * w[ic];
        acc += bf16_bits_to_float(sk2q[(size_t)b * 1024 + oc * 16 + p]) * invs2;
        float v = fminf(fmaxf(acc, 0.f), 10.f);
        o[oc * 16 + p] = v;
        lmax = fmaxf(lmax, v);
    }
    block_max_spread(lmax, m5arr, red4);
}

// ---------------- head: fq(a5) -> mean(4x4) -> linear ----------------
__global__ __launch_bounds__(64) void k_head(const float* __restrict__ a5,
                                             const unsigned* m5arr,
                                             const float* __restrict__ wlq,
                                             const float* __restrict__ blq,
                                             float* __restrict__ out) {
    __shared__ float h[64];
    __shared__ float bc0;
    int b = blockIdx.x, c = threadIdx.x;
    float m5 = load_spread_max(m5arr, &bc0);
    float s5 = 127.f / m5;
    const float* ai = a5 + (size_t)b * 1024 + c * 16;
    float sum = 0.f;
#pragma unroll
    for (int p = 0; p < 16; p++) sum += fq(ai[p], s5, 127.f);
    h[c] = sum * (1.f / 16.f);
    __syncthreads();
    if (c < 10) {
        float acc = blq[c];
        const float* w = wlq + c * 64;
        for (int ic = 0; ic < 64; ic++) acc = fmaf(h[ic], w[ic], acc);
        out[(size_t)b * 10 + c] = acc;
    }
}

// ---------------- launch ----------------
extern "C" void kernel_launch(void* const* d_in, const int* in_sizes, int n_in,
                              void* d_out, int out_size, void* d_ws, size_t ws_size,
                              hipStream_t stream) {
    const float* x  = (const float*)d_in[0];
    const float* w1 = (const float*)d_in[1];
    const float* b1 = (const float*)d_in[2];
    const float* w2 = (const float*)d_in[3];
    const float* b2 = (const float*)d_in[4];
    const float* w3 = (const float*)d_in[5];
    const float* b3 = (const float*)d_in[6];
    const float* w4 = (const float*)d_in[7];
    const float* b4 = (const float*)d_in[8];
    const float* w5 = (const float*)d_in[9];
    const float* b5 = (const float*)d_in[10];
    const float* wl = (const float*)d_in[11];
    const float* bl = (const float*)d_in[12];

    if (ws_size < WS_FLOATS_NEEDED * sizeof(float)) return;

    float* ws = (float*)d_ws;
    unsigned* slots = (unsigned*)d_ws;
    unsigned* marr[6];
    for (int k = 0; k < 6; k++) marr[k] = slots + OFF_MAXARR + k * 1024;
    short* w1i = (short*)(ws + OFF_W1I);
    short* w2i = (short*)(ws + OFF_W2I);
    short* w3i = (short*)(ws + OFF_W3I);

    hipMemsetAsync(d_ws, 0, 32768, stream);   // scalar consts + 6 spread-max arrays

    PrepArgs P;
    const float* srcs[12] = {w1, w2, w3, w4, w5, wl, b1, b2, b3, b4, b5, bl};
    const int    ns[12]   = {288, 18432, 1024, 2304, 1024, 640, 32, 64, 16, 16, 64, 10};
    const int    offs[12] = {OFF_W1Q, OFF_W2Q, OFF_W3Q, OFF_W4Q, OFF_W5Q, OFF_WLQ,
                             OFF_B1Q, OFF_B2Q, OFF_B3Q, OFF_B4Q, OFF_B5Q, OFF_BLQ};
    const float  mv[12]   = {127.f, 127.f, 127.f, 127.f, 127.f, 127.f,
                             32767.f, 32767.f, 32767.f, 32767.f, 32767.f, 32767.f};
    for (int i = 0; i < 12; i++) {
        P.src[i] = srcs[i];
        P.dst[i] = ws + offs[i];
        P.n[i] = ns[i];
        P.maxv[i] = mv[i];
    }
    P.w1 = w1; P.w1i = w1i; P.inv1 = ws + 8;
    P.w2 = w2; P.w2i = w2i; P.inv2 = ws + 6;
    P.w3 = w3; P.w3i = w3i; P.inv3 = ws + 7;
    P.x = (const float4*)x; P.n4 = BATCH * 256; P.xarr = marr[0];

    k_prep<<<15 + 256, 256, 0, stream>>>(P);
    k_s1<<<BATCH / 4, 256, 0, stream>>>(x, w1i, ws + OFF_B1Q, marr[0], ws + 8,
                                        ws + OFF_SK1F, marr[1]);
    k_s2<<<BATCH / 4, 256, 0, stream>>>(x, w1i, ws + OFF_B1Q, w2i, ws + OFF_B2Q,
                                        ws + OFF_SK1F, marr[0], marr[1], ws + 8, ws + 6,
                                        ws + OFF_V2, marr[2]);
    k_s3<<<BATCH / 4, 256, 0, stream>>>(ws + OFF_V2, w3i, ws + OFF_B3Q, marr[2], ws + 7,
                                        ws + OFF_A3, (short*)(ws + OFF_SK2I), marr[3]);
    k_conv4<<<BATCH, 256, 0, stream>>>(ws + OFF_A3, ws + OFF_W4Q, ws + OFF_B4Q, marr[3],
                                       ws + OFF_A4, marr[4]);
    k_conv5<<<BATCH, 256, 0, stream>>>(ws + OFF_A4, ws + OFF_W5Q, ws + OFF_B5Q,
                                       (const short*)(ws + OFF_SK2I), marr[2], marr[4],
                                       ws + OFF_A5, marr[5]);
    k_head<<<BATCH, 64, 0, stream>>>(ws + OFF_A5, marr[5], ws + OFF_WLQ, ws + OFF_BLQ,
                                     (float*)d_out);
}